// Round 5
// baseline (611.644 us; speedup 1.0000x reference)
//
#include <hip/hip_runtime.h>
#include <hip/hip_bf16.h>

constexpr int Ej  = 294912;  // total edges
constexpr int EPG = 1152;    // edges per graph
constexpr int WC2 = 144;     // fused-GEMM cols per head: A64 | V64 | r8:8 | cD | cS | pad6
constexpr int SPF = 132;     // scores fp32 row stride (floats); bf16 Wmat row lives at hw d*264
constexpr int HBS = 72;      // hB / A-matrix bf16 row stride (halfwords)
constexpr int VTS = 136;     // Vt bf16 row stride (halfwords)

typedef __attribute__((ext_vector_type(8))) short short8;   // 8 bf16 (MFMA A/B frag)
typedef __attribute__((ext_vector_type(4))) float f32x4;    // MFMA C/D frag

// fp32 -> bf16 bits, round-to-nearest-even
__device__ __forceinline__ unsigned short f2bf(float f) {
  unsigned u = __float_as_uint(f);
  u += 0x7FFFu + ((u >> 16) & 1u);
  return (unsigned short)(u >> 16);
}
__device__ __forceinline__ float bf2f(unsigned short b) {
  return __uint_as_float(((unsigned)b) << 16);
}
// DPP helpers: reductions within aligned 8-lane groups, pure VALU (no LDS pipe).
template <int CTRL>
__device__ __forceinline__ float dppf(float x) {
  return __int_as_float(__builtin_amdgcn_update_dpp(0, __float_as_int(x), CTRL, 0xf, 0xf, true));
}
// 0xB1 = quad_perm xor1, 0x4E = quad_perm xor2, 0x141 = row_half_mirror (i<->7-i in 8)
__device__ __forceinline__ float grp8_sum(float x) {
  x += dppf<0xB1>(x); x += dppf<0x4E>(x); x += dppf<0x141>(x); return x;
}
__device__ __forceinline__ float grp8_max(float x) {
  x = fmaxf(x, dppf<0xB1>(x)); x = fmaxf(x, dppf<0x4E>(x)); x = fmaxf(x, dppf<0x141>(x));
  return x;
}
// 64-lane sum via DPP. Result valid in lane 63.
__device__ __forceinline__ float wave_red_sum(float x) {
  x += __int_as_float(__builtin_amdgcn_update_dpp(0, __float_as_int(x), 0x111, 0xf, 0xf, true));
  x += __int_as_float(__builtin_amdgcn_update_dpp(0, __float_as_int(x), 0x112, 0xf, 0xf, true));
  x += __int_as_float(__builtin_amdgcn_update_dpp(0, __float_as_int(x), 0x114, 0xf, 0xf, true));
  x += __int_as_float(__builtin_amdgcn_update_dpp(0, __float_as_int(x), 0x118, 0xf, 0xf, true));
  x += __int_as_float(__builtin_amdgcn_update_dpp(0, __float_as_int(x), 0x142, 0xf, 0xf, true));
  x += __int_as_float(__builtin_amdgcn_update_dpp(0, __float_as_int(x), 0x143, 0xf, 0xf, true));
  return x;
}

// G[l][h][a][c] = sum_d W_edge[a,d]*We_l[d][h64+c];  bb[l][h][c] = be + b_edge@We
__global__ void k_prep2(const float* __restrict__ We, const float* __restrict__ be,
                        const float* __restrict__ W_edge, const float* __restrict__ b_edge,
                        float* __restrict__ G, float* __restrict__ bb) {
  int tid = blockIdx.x * 256 + threadIdx.x;  // 8192 + 1024
  if (tid < 8192) {
    int l = tid >> 11, rem = tid & 2047;
    int hh = rem >> 9, a = (rem >> 6) & 7, c = rem & 63;
    float acc = 0.f;
#pragma unroll 8
    for (int d = 0; d < 64; ++d)
      acc += W_edge[a * 64 + d] * We[l * 16384 + d * 256 + hh * 64 + c];
    G[tid] = acc;
  } else if (tid < 9216) {
    int t = tid - 8192;
    int l = t >> 8, rem = t & 255;
    int hh = rem >> 6, c = rem & 63;
    float acc = be[l * 256 + hh * 64 + c];
#pragma unroll 8
    for (int d = 0; d < 64; ++d)
      acc += b_edge[d] * We[l * 16384 + d * 256 + hh * 64 + c];
    bb[t] = acc;
  }
}

// WcatT [lh][col][kk] bf16 + bcatT fp32.  (see r1-r3 for column semantics)
__global__ void __launch_bounds__(256) k_prepW(
    const float* __restrict__ Wq, const float* __restrict__ bq,
    const float* __restrict__ Wk, const float* __restrict__ bk,
    const float* __restrict__ Wv, const float* __restrict__ bv,
    const float* __restrict__ Gbuf, const float* __restrict__ bbuf,
    unsigned short* __restrict__ WcatT, float* __restrict__ bcatT) {
  int t = blockIdx.x * 256 + threadIdx.x;  // 16*144*64
  if (t >= 16 * WC2 * 64) return;
  int kk = t & 63;
  int col = (t >> 6) % WC2;
  int lh = t / (WC2 * 64);
  int h = lh & 3, l = lh >> 2;
  const float* Wq_l = Wq + l * 16384;
  const float* Wk_l = Wk + l * 16384;
  const float* bq_l = bq + l * 256;
  const float* bk_l = bk + l * 256;
  float w = 0.f, bias = 0.f;
  if (col < 64) {
    float s = 0.f;
#pragma unroll 8
    for (int i = 0; i < 64; ++i)
      s += Wq_l[kk * 256 + h * 64 + i] * Wk_l[col * 256 + h * 64 + i];
    w = 0.125f * s;
  } else if (col < 128) {
    int j = col - 64;
    w = Wv[l * 16384 + kk * 256 + h * 64 + j];
    bias = bv[l * 256 + h * 64 + j];
  } else if (col < 136) {
    int a = col - 128;
    const float* Grow = Gbuf + l * 2048 + h * 512 + a * 64;
    float s = 0.f, sb = 0.f;
#pragma unroll 8
    for (int i = 0; i < 64; ++i) {
      s  += Wq_l[kk * 256 + h * 64 + i] * Grow[i];
      sb += bq_l[h * 64 + i] * Grow[i];
    }
    w = 0.125f * s; bias = 0.125f * sb;
  } else if (col == 136) {
    float s = 0.f, sb = 0.f;
#pragma unroll 8
    for (int i = 0; i < 64; ++i) {
      float bkb = bk_l[h * 64 + i] + bbuf[l * 256 + h * 64 + i];
      s  += Wq_l[kk * 256 + h * 64 + i] * bkb;
      sb += bq_l[h * 64 + i] * bkb;
    }
    w = 0.125f * s; bias = 0.125f * sb;
  } else if (col == 137) {
    float s = 0.f;
#pragma unroll 8
    for (int i = 0; i < 64; ++i)
      s += Wk_l[kk * 256 + h * 64 + i] * bq_l[h * 64 + i];
    w = 0.125f * s;
  }
  WcatT[(size_t)(lh * WC2 + col) * 64 + kk] = f2bf(w);
  if (kk == 0) bcatT[lh * WC2 + col] = bias;
}

// Counting sort of each graph's edges by key = dst*128+src. Emits
// sortedSR (src | duprank<<8 | dst<<16), sortedEA (edge_attr reordered), offs[g][129].
__global__ void __launch_bounds__(256) k_sort(const int* __restrict__ ei,
                                              const float* __restrict__ edge_attr,
                                              int* __restrict__ sortedSR,
                                              float* __restrict__ sortedEA,
                                              int* __restrict__ offs) {
  __shared__ unsigned hist[16384];    // 64 KB
  __shared__ unsigned cursor[16384];  // 64 KB
  __shared__ unsigned csum[256];
  int g = blockIdx.x, tid = threadIdx.x;
#pragma unroll
  for (int i = 0; i < 64; ++i) { hist[tid * 64 + i] = 0u; cursor[tid * 64 + i] = 0u; }
  __syncthreads();
  for (int e = tid; e < EPG; e += 256) {
    int s = ei[g * EPG + e] - g * 128;
    int d = ei[Ej + g * EPG + e] - g * 128;
    atomicAdd(&hist[d * 128 + s], 1u);
  }
  __syncthreads();
  // exclusive scan (chunk-serial + single-thread chunk scan)
  unsigned acc = 0;
  int base = tid * 64;
#pragma unroll
  for (int i = 0; i < 64; ++i) { unsigned t = hist[base + i]; hist[base + i] = acc; acc += t; }
  csum[tid] = acc;
  __syncthreads();
  if (tid == 0) {
    unsigned run = 0;
    for (int j = 0; j < 256; ++j) { unsigned t = csum[j]; csum[j] = run; run += t; }
  }
  __syncthreads();
  unsigned off = csum[tid];
#pragma unroll
  for (int i = 0; i < 64; ++i) hist[base + i] += off;
  __syncthreads();
  if (tid < 128) offs[g * 129 + tid] = (int)hist[tid * 128];
  if (tid == 0) offs[g * 129 + 128] = EPG;
  // scatter (order within identical (dst,src) irrelevant; rank via cursor)
  for (int e = tid; e < EPG; e += 256) {
    int s = ei[g * EPG + e] - g * 128;
    int d = ei[Ej + g * EPG + e] - g * 128;
    int key = d * 128 + s;
    unsigned r = atomicAdd(&cursor[key], 1u);
    unsigned pos = hist[key] + r;
    sortedSR[g * EPG + pos] = s | ((int)min(r, 3u) << 8) | (d << 16);
    const float4* ep = (const float4*)(edge_attr + ((size_t)g * EPG + e) * 8);
    float4* op = (float4*)(sortedEA + ((size_t)g * EPG + pos) * 8);
    op[0] = ep[0]; op[1] = ep[1];
  }
}

// One block per graph, 1024 threads (16 waves, 4/SIMD). 4 barriers per head:
// P0 (qkv GEMM, WT from global) | P1 (scores MFMA + dense dot(ea,r8)->dotL) |
// PD (per-dst softmax via DPP, no atomics; ea reloaded transiently in exp pass) |
// P5 (Wmat@Vt MFMA + epilogue). LDS 157184 B -> 1 block/CU.
__global__ void __launch_bounds__(1024, 4) k_fused(
    const float* __restrict__ x, const float* __restrict__ W_node, const float* __restrict__ b_node,
    const unsigned short* __restrict__ WcatT, const float* __restrict__ bcatT,
    const int* __restrict__ sortedSR, const float* __restrict__ sortedEA,
    const int* __restrict__ offs,
    const float* __restrict__ Gbuf, const float* __restrict__ bbuf,
    const float* __restrict__ Wskip, const float* __restrict__ bskip,
    const float* __restrict__ Wd, const float* __restrict__ bd,
    const float* __restrict__ Wo, const float* __restrict__ bo,
    float* __restrict__ out) {
  __shared__ float SS[128 * SPF];           // 67584 B: scores fp32 / Wmat bf16 (in-row) / Wskip
  __shared__ float h32[128 * 68];           // 34816 B: resident fp32 h
  __shared__ unsigned short hB[128 * HBS];  // 18432 B: bf16 h
  __shared__ unsigned short AV[128 * HBS];  // 18432 B: A-matrix (P0-P1) then Vt 64xVTS (PD-P5)
  __shared__ float r8L[128 * 8];            // 4096
  __shared__ float t8L[128 * 9];            // 4608
  __shared__ float dotL[EPG];               // 4608: dot(ea, r8[dst]) per sorted edge
  __shared__ float sL[128];                 // 512
  __shared__ float cDL[128];                // 512
  __shared__ float cSL[128];                // 512
  __shared__ float GhL[512];                // 2048
  __shared__ float vembL[256];              // 1024

  int g = blockIdx.x, tid = threadIdx.x;
  int lane = tid & 63, m16 = lane & 15, quad = lane >> 4, wv = tid >> 6;  // wv 0..15
  const int strip = wv >> 1, ch = wv & 1;
  const int m0 = strip * 16;

  // node encoder -> h32
  for (int idx = tid; idx < 8192; idx += 1024) {
    int n = idx >> 6, c = idx & 63;
    const float* xr = x + (size_t)(g * 128 + n) * 16;
    float acc = b_node[c];
#pragma unroll
    for (int d = 0; d < 16; ++d) acc += xr[d] * W_node[d * 64 + c];
    h32[n * 68 + c] = acc;
  }

  // per-dst segment (8 lanes per dst)
  const int dD = tid >> 3, sub = tid & 7;
  const int ofsD = offs[g * 129 + dD];
  const int cntD = offs[g * 129 + dD + 1] - ofsD;
  const int dsw = (dD & 7) << 4;  // XOR swizzle (float idx for scores, hw idx for Wmat)
  const int gE = g * EPG;
  __syncthreads();

  for (int l = 0; l < 4; ++l) {
    // ---- stage hB = bf16(h32)
    {
      int row = tid >> 3, c8 = tid & 7;
      const float* hr = &h32[row * 68 + c8 * 8];
      float4 a0 = *(const float4*)hr, a1 = *(const float4*)(hr + 4);
      uint4 hp;
      hp.x = f2bf(a0.x) | ((unsigned)f2bf(a0.y) << 16);
      hp.y = f2bf(a0.z) | ((unsigned)f2bf(a0.w) << 16);
      hp.z = f2bf(a1.x) | ((unsigned)f2bf(a1.y) << 16);
      hp.w = f2bf(a1.z) | ((unsigned)f2bf(a1.w) << 16);
      *(uint4*)&hB[row * HBS + c8 * 8] = hp;
    }
    __syncthreads();

    f32x4 accP5_0 = {0.f, 0.f, 0.f, 0.f};
    f32x4 accP5_1 = {0.f, 0.f, 0.f, 0.f};
    float4 wskL;

    for (int h = 0; h < 4; ++h) {
      const int lh = l * 4 + h;
      // ---- P0: qkv GEMM. ch0: A-tiles 0..3 + special; ch1: V-tiles. WT direct from global.
      const float* bcTl = bcatT + (size_t)lh * WC2;
      const unsigned short* WTg = WcatT + (size_t)lh * WC2 * 64;
      f32x4 vf0, vf1, vf2, vf3;
      {
        if (tid < 512) GhL[tid] = Gbuf[l * 2048 + h * 512 + tid];
        const short8 a0 = *(const short8*)&hB[(m0 + m16) * HBS + quad * 8];
        const short8 a1 = *(const short8*)&hB[(m0 + m16) * HBS + 32 + quad * 8];
#pragma unroll
        for (int j = 0; j < 4; ++j) {
          int n0 = (ch * 4 + j) * 16;
          const unsigned short* wb = WTg + (size_t)(n0 + m16) * 64 + quad * 8;
          const short8 b0 = *(const short8*)wb;
          const short8 b1 = *(const short8*)(wb + 32);
          float bias = bcTl[n0 + m16];
          f32x4 acc = {bias, bias, bias, bias};
          acc = __builtin_amdgcn_mfma_f32_16x16x32_bf16(a0, b0, acc, 0, 0, 0);
          acc = __builtin_amdgcn_mfma_f32_16x16x32_bf16(a1, b1, acc, 0, 0, 0);
          if (ch == 0) {
#pragma unroll
            for (int r = 0; r < 4; ++r)
              AV[(m0 + quad * 4 + r) * HBS + n0 + m16] = f2bf(acc[r]);
          } else {
            if (j == 0) vf0 = acc;
            else if (j == 1) vf1 = acc;
            else if (j == 2) vf2 = acc;
            else vf3 = acc;
          }
        }
        if (ch == 0) {  // special tile n0=128: r8 | cD | cS
          const unsigned short* wb = WTg + (size_t)(128 + m16) * 64 + quad * 8;
          const short8 b0 = *(const short8*)wb;
          const short8 b1 = *(const short8*)(wb + 32);
          float bias = bcTl[128 + m16];
          f32x4 acc = {bias, bias, bias, bias};
          acc = __builtin_amdgcn_mfma_f32_16x16x32_bf16(a0, b0, acc, 0, 0, 0);
          acc = __builtin_amdgcn_mfma_f32_16x16x32_bf16(a1, b1, acc, 0, 0, 0);
          if (m16 < 8) {
#pragma unroll
            for (int r = 0; r < 4; ++r) r8L[(m0 + quad * 4 + r) * 8 + m16] = acc[r];
          } else if (m16 == 8) {
#pragma unroll
            for (int r = 0; r < 4; ++r) cDL[m0 + quad * 4 + r] = acc[r];
          } else if (m16 == 9) {
#pragma unroll
            for (int r = 0; r < 4; ++r) cSL[m0 + quad * 4 + r] = acc[r];
          }
        }
      }
      __syncthreads();

      // ---- P1: scores = A @ hB^T -> SS fp32 (col XOR-swizzled)  ||  dense dot(ea,r8)->dotL
      {
        // dense per-edge dot, coalesced (overlaps with MFMA below)
        {
          int sr0 = sortedSR[gE + tid];
          int d0 = (sr0 >> 16) & 127;
          float4 a0 = *(const float4*)(sortedEA + (size_t)(gE + tid) * 8);
          float4 a1 = *(const float4*)(sortedEA + (size_t)(gE + tid) * 8 + 4);
          float4 r80 = *(const float4*)&r8L[d0 * 8];
          float4 r81 = *(const float4*)&r8L[d0 * 8 + 4];
          dotL[tid] = a0.x * r80.x + a0.y * r80.y + a0.z * r80.z + a0.w * r80.w
                    + a1.x * r81.x + a1.y * r81.y + a1.z * r81.z + a1.w * r81.w;
          if (tid < 128) {
            int e1i = 1024 + tid;
            int sr1 = sortedSR[gE + e1i];
            int d1 = (sr1 >> 16) & 127;
            float4 b0 = *(const float4*)(sortedEA + (size_t)(gE + e1i) * 8);
            float4 b1 = *(const float4*)(sortedEA + (size_t)(gE + e1i) * 8 + 4);
            float4 s80 = *(const float4*)&r8L[d1 * 8];
            float4 s81 = *(const float4*)&r8L[d1 * 8 + 4];
            dotL[e1i] = b0.x * s80.x + b0.y * s80.y + b0.z * s80.z + b0.w * s80.w
                      + b1.x * s81.x + b1.y * s81.y + b1.z * s81.z + b1.w * s81.w;
          }
        }
        const short8 a0 = *(const short8*)&AV[(m0 + m16) * HBS + quad * 8];
        const short8 a1 = *(const short8*)&AV[(m0 + m16) * HBS + 32 + quad * 8];
#pragma unroll
        for (int t = 0; t < 4; ++t) {
          int src0 = ch * 64 + t * 16;
          const short8 b0 = *(const short8*)&hB[(src0 + m16) * HBS + quad * 8];
          const short8 b1 = *(const short8*)&hB[(src0 + m16) * HBS + 32 + quad * 8];
          f32x4 acc = {0.f, 0.f, 0.f, 0.f};
          acc = __builtin_amdgcn_mfma_f32_16x16x32_bf16(a0, b0, acc, 0, 0, 0);
          acc = __builtin_amdgcn_mfma_f32_16x16x32_bf16(a1, b1, acc, 0, 0, 0);
#pragma unroll
          for (int r = 0; r < 4; ++r) {
            int row = m0 + quad * 4 + r;
            SS[row * SPF + ((src0 + m16) ^ ((row & 7) << 4))] = acc[r];
          }
        }
      }
      __syncthreads();

      // ---- PD: V-deposit; per-dst softmax (DPP, no atomics, low reg); zero+scatter Wmat bf16
      {
        if (ch == 1) {  // deposit V frags -> Vt (transposed bf16)
#pragma unroll
          for (int r = 0; r < 4; ++r) AV[(m16) * VTS + m0 + quad * 4 + r] = f2bf(vf0[r]);
#pragma unroll
          for (int r = 0; r < 4; ++r) AV[(16 + m16) * VTS + m0 + quad * 4 + r] = f2bf(vf1[r]);
#pragma unroll
          for (int r = 0; r < 4; ++r) AV[(32 + m16) * VTS + m0 + quad * 4 + r] = f2bf(vf2[r]);
#pragma unroll
          for (int r = 0; r < 4; ++r) AV[(48 + m16) * VTS + m0 + quad * 4 + r] = f2bf(vf3[r]);
        }
        int sr[5];
        float al[5];
#pragma unroll
        for (int it = 0; it < 5; ++it) {
          int p = sub + it * 8;
          sr[it] = (p < cntD) ? sortedSR[gE + ofsD + p] : -1;
        }
        float cD = cDL[dD];
#pragma unroll
        for (int it = 0; it < 5; ++it) {
          float a = -3.4e38f;
          if (sr[it] >= 0) {
            int src = sr[it] & 127;
            a = SS[dD * SPF + (src ^ dsw)] + cD + cSL[src] + dotL[ofsD + sub + it * 8];
          }
          al[it] = a;
        }
        float m = fmaxf(fmaxf(fmaxf(al[0], al[1]), fmaxf(al[2], al[3])), al[4]);
        m = grp8_max(m);
        // exp pass: reload ea transiently; accumulate unnormalized s and t8p
        float s = 0.f;
        float t8p[8] = {0.f, 0.f, 0.f, 0.f, 0.f, 0.f, 0.f, 0.f};
#pragma unroll
        for (int it = 0; it < 5; ++it) {
          float e = 0.f;
          if (sr[it] >= 0) {
            e = expf(al[it] - m);
            int eidx = gE + ofsD + sub + it * 8;
            float4 e0 = *(const float4*)(sortedEA + (size_t)eidx * 8);
            float4 e1 = *(const float4*)(sortedEA + (size_t)eidx * 8 + 4);
            t8p[0] += e * e0.x; t8p[1] += e * e0.y;
            t8p[2] += e * e0.z; t8p[3] += e * e0.w;
            t8p[4] += e * e1.x; t8p[5] += e * e1.y;
            t8p[6] += e * e1.z; t8p[7] += e * e1.w;
          }
          al[it] = e;
          s += e;
        }
        s = grp8_sum(s);
#pragma unroll
        for (int k = 0; k < 8; ++k) t8p[k] = grp8_sum(t8p[k]);
        float inv = 1.f / fmaxf(s, 1e-16f);
        if (sub == 0) {
#pragma unroll
          for (int k = 0; k < 8; ++k) t8L[dD * 9 + k] = t8p[k] * inv;
          sL[dD] = s;
        }
        // zero this row's Wmat footprint, then scatter w (same wave; LDS in-order)
        __builtin_amdgcn_sched_barrier(0);
        unsigned short* Wu = (unsigned short*)SS;
        int rowb = dD * 264;
        int z0 = (sub * 16) ^ dsw;
        uint4 zz = make_uint4(0u, 0u, 0u, 0u);
        *(uint4*)&Wu[rowb + z0] = zz;
        *(uint4*)&Wu[rowb + z0 + 8] = zz;
        __builtin_amdgcn_sched_barrier(0);
        bool anyDup = false;
#pragma unroll
        for (int it = 0; it < 5; ++it) {
          if (sr[it] >= 0) {
            int rk = (sr[it] >> 8) & 3;
            anyDup |= (rk != 0);
            if (rk == 0) Wu[rowb + ((sr[it] & 127) ^ dsw)] = f2bf(al[it] * inv);
          }
        }
        if (__any(anyDup)) {  // rare duplicate (dst,src) edges: rank-ordered accumulate
#pragma unroll
          for (int rk = 1; rk < 4; ++rk) {
            __builtin_amdgcn_sched_barrier(0);
#pragma unroll
            for (int it = 0; it < 5; ++it) {
              if (sr[it] >= 0 && (((sr[it] >> 8) & 3) == rk)) {
                int slot = rowb + ((sr[it] & 127) ^ dsw);
                Wu[slot] = f2bf(bf2f(Wu[slot]) + al[it] * inv);
              }
            }
          }
        }
      }
      __syncthreads();

      // ---- P5: accP5 += Wmat@Vt (MFMA) + t8@G + (s>0)*bb
      {
        if (h == 3) wskL = ((const float4*)(Wskip + (size_t)l * 4096))[tid];
        const unsigned short* Wu = (const unsigned short*)SS;
        int row0 = m0 + m16;
        short8 a_[4];
#pragma unroll
        for (int ks = 0; ks < 4; ++ks)
          a_[ks] = *(const short8*)&Wu[row0 * 264 + (((ks * 32) + quad * 8) ^ ((row0 & 7) << 4))];
#pragma unroll
        for (int t2 = 0; t2 < 2; ++t2) {
          int c0 = ch * 32 + t2 * 16;
          f32x4 acc = (t2 == 0) ? accP5_0 : accP5_1;
#pragma unroll
          for (int ks = 0; ks < 4; ++ks) {
            const short8 b = *(const short8*)&AV[(c0 + m16) * VTS + ks * 32 + quad * 8];
            acc = __builtin_amdgcn_mfma_f32_16x16x32_bf16(a_[ks], b, acc, 0, 0, 0);
          }
          int col = c0 + m16;
          float bbv = bbuf[l * 256 + h * 64 + col];
          float gcol[8];
#pragma unroll
          for (int a8 = 0; a8 < 8; ++a8) gcol[a8] = GhL[a8 * 64 + col];
#pragma unroll
          for (int r = 0; r < 4; ++r) {
            int row = m0 + quad * 4 + r;
            float add = (sL[row] > 0.f) ? bbv : 0.f;
#pragma unroll
            for (int a8 = 0; a8 < 8; ++a8) add += t8L[row * 9 + a8] * gcol[a8];
            acc[r] += add;
          }
          if (t2 == 0) accP5_0 = acc; else accP5_1 = acc;
        }
      }
      __syncthreads();
    }  // heads

    // ---- update: out = 0.25*acc + h@Wskip+bskip ; vemb ; h += out
    *(float4*)&SS[tid * 4] = wskL;  // Wskip_l -> SS[0..4096)
    __syncthreads();
    {
      float sk0[4], sk1[4];
#pragma unroll
      for (int t2 = 0; t2 < 2; ++t2) {
        int col = ch * 32 + t2 * 16 + m16;
        float bsv = bskip[l * 64 + col];
#pragma unroll
        for (int r = 0; r < 4; ++r) {
          int row = m0 + quad * 4 + r;
          float s = bsv;
#pragma unroll 8
          for (int d = 0; d < 64; ++d) s += h32[row * 68 + d] * SS[d * 64 + col];
          if (t2 == 0) sk0[r] = s; else sk1[r] = s;
        }
      }
      __syncthreads();  // all h32 reads done before in-place writes
#pragma unroll
      for (int t2 = 0; t2 < 2; ++t2) {
        int col = ch * 32 + t2 * 16 + m16;
#pragma unroll
        for (int r = 0; r < 4; ++r) {
          int row = m0 + quad * 4 + r;
          float av = (t2 == 0) ? accP5_0[r] : accP5_1[r];
          float outv = av * 0.25f + ((t2 == 0) ? sk0[r] : sk1[r]);
          float hnew = outv + h32[row * 68 + col];
          h32[row * 68 + col] = hnew;
          if (row == 127) vembL[l * 64 + col] = outv;
        }
      }
    }
    __syncthreads();
  }  // layers

  // ---- head: pool = vemb @ W_down + b_down; out = sigmoid(pool @ W_out + b_out)
  {
    float part = 0.f;
#pragma unroll
    for (int j2 = 0; j2 < 16; ++j2) {
      int j = wv * 16 + j2;
      part += vembL[j] * Wd[j * 64 + lane];
    }
    SS[wv * 64 + lane] = part;
    __syncthreads();
    if (wv == 0) {
      float acc = bd[lane];
#pragma unroll
      for (int w2 = 0; w2 < 16; ++w2) acc += SS[w2 * 64 + lane];
      float p = acc * Wo[lane];
      p = wave_red_sum(p);
      if (lane == 63) out[g] = 1.f / (1.f + expf(-(p + bo[0])));
    }
  }
}

extern "C" void kernel_launch(void* const* d_in, const int* in_sizes, int n_in,
                              void* d_out, int out_size, void* d_ws, size_t ws_size,
                              hipStream_t stream) {
  const float* x         = (const float*)d_in[0];
  const float* edge_attr = (const float*)d_in[1];
  const int*   ei        = (const int*)d_in[2];
  const float* W_node = (const float*)d_in[4];
  const float* b_node = (const float*)d_in[5];
  const float* W_edge = (const float*)d_in[6];
  const float* b_edge = (const float*)d_in[7];
  const float* Wq = (const float*)d_in[8];
  const float* bq = (const float*)d_in[9];
  const float* Wk = (const float*)d_in[10];
  const float* bk = (const float*)d_in[11];
  const float* Wv = (const float*)d_in[12];
  const float* bv = (const float*)d_in[13];
  const float* We = (const float*)d_in[14];
  const float* be = (const float*)d_in[15];
  const float* Wskip = (const float*)d_in[16];
  const float* bskip = (const float*)d_in[17];
  const float* W_down = (const float*)d_in[18];
  const float* b_down = (const float*)d_in[19];
  const float* W_out  = (const float*)d_in[20];
  const float* b_out  = (const float*)d_in[21];
  float* out = (float*)d_out;

  // workspace carve (~11.2 MB)
  float* p = (float*)d_ws;
  float* Gbuf  = p; p += 8192;
  float* bbuf  = p; p += 1024;
  float* bcatT = p; p += 16 * WC2;                  // 2304 floats
  unsigned short* WcatT = (unsigned short*)p; p += 16 * WC2 * 64 / 2;  // bf16, 294912 B
  int* offsB   = (int*)p; p += 256 * 129;           // 132 KB
  int* sortedSR = (int*)p; p += Ej;                 // 1.18 MB
  float* sortedEA = p; p += (size_t)Ej * 8;         // 9.44 MB

  k_prep2<<<36, 256, 0, stream>>>(We, be, W_edge, b_edge, Gbuf, bbuf);
  k_prepW<<<(16 * WC2 * 64) / 256, 256, 0, stream>>>(Wq, bq, Wk, bk, Wv, bv, Gbuf, bbuf,
                                                     WcatT, bcatT);
  k_sort<<<256, 256, 0, stream>>>(ei, edge_attr, sortedSR, sortedEA, offsB);
  k_fused<<<256, 1024, 0, stream>>>(x, W_node, b_node, WcatT, bcatT,
                                    sortedSR, sortedEA, offsB,
                                    Gbuf, bbuf, Wskip, bskip, W_down, b_down, W_out, b_out,
                                    out);
}

// Round 6
// 395.378 us; speedup vs baseline: 1.5470x; 1.5470x over previous
//
#include <hip/hip_runtime.h>
#include <hip/hip_bf16.h>

constexpr int Ej  = 294912;  // total edges
constexpr int EPG = 1152;    // edges per graph
constexpr int WC2 = 144;     // fused-GEMM cols per head: A64 | V64 | r8:8 | cD | cS | pad6
constexpr int SPF = 132;     // scores fp32 row stride (floats); bf16 Wmat row lives at hw d*264
constexpr int HBS = 72;      // hB / A-matrix bf16 row stride (halfwords)
constexpr int VTS = 136;     // Vt bf16 row stride (halfwords)

typedef __attribute__((ext_vector_type(8))) short short8;   // 8 bf16 (MFMA A/B frag)
typedef __attribute__((ext_vector_type(4))) float f32x4;    // MFMA C/D frag

// fp32 -> bf16 bits, round-to-nearest-even
__device__ __forceinline__ unsigned short f2bf(float f) {
  unsigned u = __float_as_uint(f);
  u += 0x7FFFu + ((u >> 16) & 1u);
  return (unsigned short)(u >> 16);
}
__device__ __forceinline__ float bf2f(unsigned short b) {
  return __uint_as_float(((unsigned)b) << 16);
}
// DPP helpers: reductions within aligned 8-lane groups, pure VALU (no LDS pipe).
template <int CTRL>
__device__ __forceinline__ float dppf(float x) {
  return __int_as_float(__builtin_amdgcn_update_dpp(0, __float_as_int(x), CTRL, 0xf, 0xf, true));
}
// 0xB1 = quad_perm xor1, 0x4E = quad_perm xor2, 0x141 = row_half_mirror (i<->7-i in 8)
__device__ __forceinline__ float grp8_sum(float x) {
  x += dppf<0xB1>(x); x += dppf<0x4E>(x); x += dppf<0x141>(x); return x;
}
__device__ __forceinline__ float grp8_max(float x) {
  x = fmaxf(x, dppf<0xB1>(x)); x = fmaxf(x, dppf<0x4E>(x)); x = fmaxf(x, dppf<0x141>(x));
  return x;
}
// 64-lane sum via DPP. Result valid in lane 63.
__device__ __forceinline__ float wave_red_sum(float x) {
  x += __int_as_float(__builtin_amdgcn_update_dpp(0, __float_as_int(x), 0x111, 0xf, 0xf, true));
  x += __int_as_float(__builtin_amdgcn_update_dpp(0, __float_as_int(x), 0x112, 0xf, 0xf, true));
  x += __int_as_float(__builtin_amdgcn_update_dpp(0, __float_as_int(x), 0x114, 0xf, 0xf, true));
  x += __int_as_float(__builtin_amdgcn_update_dpp(0, __float_as_int(x), 0x118, 0xf, 0xf, true));
  x += __int_as_float(__builtin_amdgcn_update_dpp(0, __float_as_int(x), 0x142, 0xf, 0xf, true));
  x += __int_as_float(__builtin_amdgcn_update_dpp(0, __float_as_int(x), 0x143, 0xf, 0xf, true));
  return x;
}

// G[l][h][a][c] = sum_d W_edge[a,d]*We_l[d][h64+c];  bb[l][h][c] = be + b_edge@We
__global__ void k_prep2(const float* __restrict__ We, const float* __restrict__ be,
                        const float* __restrict__ W_edge, const float* __restrict__ b_edge,
                        float* __restrict__ G, float* __restrict__ bb) {
  int tid = blockIdx.x * 256 + threadIdx.x;  // 8192 + 1024
  if (tid < 8192) {
    int l = tid >> 11, rem = tid & 2047;
    int hh = rem >> 9, a = (rem >> 6) & 7, c = rem & 63;
    float acc = 0.f;
#pragma unroll 8
    for (int d = 0; d < 64; ++d)
      acc += W_edge[a * 64 + d] * We[l * 16384 + d * 256 + hh * 64 + c];
    G[tid] = acc;
  } else if (tid < 9216) {
    int t = tid - 8192;
    int l = t >> 8, rem = t & 255;
    int hh = rem >> 6, c = rem & 63;
    float acc = be[l * 256 + hh * 64 + c];
#pragma unroll 8
    for (int d = 0; d < 64; ++d)
      acc += b_edge[d] * We[l * 16384 + d * 256 + hh * 64 + c];
    bb[t] = acc;
  }
}

// WcatT [lh][col][kk] bf16 + bcatT fp32.  (see earlier rounds for column semantics)
__global__ void __launch_bounds__(256) k_prepW(
    const float* __restrict__ Wq, const float* __restrict__ bq,
    const float* __restrict__ Wk, const float* __restrict__ bk,
    const float* __restrict__ Wv, const float* __restrict__ bv,
    const float* __restrict__ Gbuf, const float* __restrict__ bbuf,
    unsigned short* __restrict__ WcatT, float* __restrict__ bcatT) {
  int t = blockIdx.x * 256 + threadIdx.x;  // 16*144*64
  if (t >= 16 * WC2 * 64) return;
  int kk = t & 63;
  int col = (t >> 6) % WC2;
  int lh = t / (WC2 * 64);
  int h = lh & 3, l = lh >> 2;
  const float* Wq_l = Wq + l * 16384;
  const float* Wk_l = Wk + l * 16384;
  const float* bq_l = bq + l * 256;
  const float* bk_l = bk + l * 256;
  float w = 0.f, bias = 0.f;
  if (col < 64) {
    float s = 0.f;
#pragma unroll 8
    for (int i = 0; i < 64; ++i)
      s += Wq_l[kk * 256 + h * 64 + i] * Wk_l[col * 256 + h * 64 + i];
    w = 0.125f * s;
  } else if (col < 128) {
    int j = col - 64;
    w = Wv[l * 16384 + kk * 256 + h * 64 + j];
    bias = bv[l * 256 + h * 64 + j];
  } else if (col < 136) {
    int a = col - 128;
    const float* Grow = Gbuf + l * 2048 + h * 512 + a * 64;
    float s = 0.f, sb = 0.f;
#pragma unroll 8
    for (int i = 0; i < 64; ++i) {
      s  += Wq_l[kk * 256 + h * 64 + i] * Grow[i];
      sb += bq_l[h * 64 + i] * Grow[i];
    }
    w = 0.125f * s; bias = 0.125f * sb;
  } else if (col == 136) {
    float s = 0.f, sb = 0.f;
#pragma unroll 8
    for (int i = 0; i < 64; ++i) {
      float bkb = bk_l[h * 64 + i] + bbuf[l * 256 + h * 64 + i];
      s  += Wq_l[kk * 256 + h * 64 + i] * bkb;
      sb += bq_l[h * 64 + i] * bkb;
    }
    w = 0.125f * s; bias = 0.125f * sb;
  } else if (col == 137) {
    float s = 0.f;
#pragma unroll 8
    for (int i = 0; i < 64; ++i)
      s += Wk_l[kk * 256 + h * 64 + i] * bq_l[h * 64 + i];
    w = 0.125f * s;
  }
  WcatT[(size_t)(lh * WC2 + col) * 64 + kk] = f2bf(w);
  if (kk == 0) bcatT[lh * WC2 + col] = bias;
}

// Counting sort of each graph's edges by key = dst*128+src. Emits
// sortedSR (src | duprank<<8 | dst<<16), sortedEA (edge_attr reordered), offs[g][129].
__global__ void __launch_bounds__(256) k_sort(const int* __restrict__ ei,
                                              const float* __restrict__ edge_attr,
                                              int* __restrict__ sortedSR,
                                              float* __restrict__ sortedEA,
                                              int* __restrict__ offs) {
  __shared__ unsigned hist[16384];    // 64 KB
  __shared__ unsigned cursor[16384];  // 64 KB
  __shared__ unsigned csum[256];
  int g = blockIdx.x, tid = threadIdx.x;
#pragma unroll
  for (int i = 0; i < 64; ++i) { hist[tid * 64 + i] = 0u; cursor[tid * 64 + i] = 0u; }
  __syncthreads();
  for (int e = tid; e < EPG; e += 256) {
    int s = ei[g * EPG + e] - g * 128;
    int d = ei[Ej + g * EPG + e] - g * 128;
    atomicAdd(&hist[d * 128 + s], 1u);
  }
  __syncthreads();
  // exclusive scan (chunk-serial + single-thread chunk scan)
  unsigned acc = 0;
  int base = tid * 64;
#pragma unroll
  for (int i = 0; i < 64; ++i) { unsigned t = hist[base + i]; hist[base + i] = acc; acc += t; }
  csum[tid] = acc;
  __syncthreads();
  if (tid == 0) {
    unsigned run = 0;
    for (int j = 0; j < 256; ++j) { unsigned t = csum[j]; csum[j] = run; run += t; }
  }
  __syncthreads();
  unsigned off = csum[tid];
#pragma unroll
  for (int i = 0; i < 64; ++i) hist[base + i] += off;
  __syncthreads();
  if (tid < 128) offs[g * 129 + tid] = (int)hist[tid * 128];
  if (tid == 0) offs[g * 129 + 128] = EPG;
  // scatter (order within identical (dst,src) irrelevant; rank via cursor)
  for (int e = tid; e < EPG; e += 256) {
    int s = ei[g * EPG + e] - g * 128;
    int d = ei[Ej + g * EPG + e] - g * 128;
    int key = d * 128 + s;
    unsigned r = atomicAdd(&cursor[key], 1u);
    unsigned pos = hist[key] + r;
    sortedSR[g * EPG + pos] = s | ((int)min(r, 3u) << 8) | (d << 16);
    const float4* ep = (const float4*)(edge_attr + ((size_t)g * EPG + e) * 8);
    float4* op = (float4*)(sortedEA + ((size_t)g * EPG + pos) * 8);
    op[0] = ep[0]; op[1] = ep[1];
  }
}

// One block per graph, 512 threads (8 waves, 2/SIMD => 256-reg/wave budget, spill-free — r3).
// Per head (5 barriers): stage(WT regs->LDS, GhL) | P0 qkv GEMM | P1 scores MFMA + dense
// dot(ea,r8)->dotL | PD per-dst softmax x2 halves (DPP, no atomics) | P5 Wmat@Vt + epilogue.
// sortedSR held in 10 persistent regs (layer/head-invariant). LDS 157184 B -> 1 block/CU.
__global__ void __launch_bounds__(512, 2) k_fused(
    const float* __restrict__ x, const float* __restrict__ W_node, const float* __restrict__ b_node,
    const unsigned short* __restrict__ WcatT, const float* __restrict__ bcatT,
    const int* __restrict__ sortedSR, const float* __restrict__ sortedEA,
    const int* __restrict__ offs,
    const float* __restrict__ Gbuf, const float* __restrict__ bbuf,
    const float* __restrict__ Wskip, const float* __restrict__ bskip,
    const float* __restrict__ Wd, const float* __restrict__ bd,
    const float* __restrict__ Wo, const float* __restrict__ bo,
    float* __restrict__ out) {
  __shared__ float SS[128 * SPF];           // 67584 B: WT stage / scores fp32 / Wmat bf16 / Wskip
  __shared__ float h32[128 * 68];           // 34816 B: resident fp32 h
  __shared__ unsigned short hB[128 * HBS];  // 18432 B: bf16 h
  __shared__ unsigned short AV[128 * HBS];  // 18432 B: A-matrix (P0-P1) then Vt 64xVTS (PD-P5)
  __shared__ float r8L[128 * 8];            // 4096
  __shared__ float t8L[128 * 9];            // 4608
  __shared__ float dotL[EPG];               // 4608: dot(ea, r8[dst]) per sorted edge
  __shared__ float sL[128];                 // 512
  __shared__ float cDL[128];                // 512
  __shared__ float cSL[128];                // 512
  __shared__ float GhL[512];                // 2048
  __shared__ float vembL[256];              // 1024

  int g = blockIdx.x, tid = threadIdx.x;
  int lane = tid & 63, m16 = lane & 15, quad = lane >> 4, wv = tid >> 6;  // wv 0..7
  const int m0 = wv * 16;  // this wave's m-strip / dst-strip everywhere
  const int gE = g * EPG;

  // prefetch WT for (l=0,h=0): 1152 uint4 over 512 threads (2.25 each)
  uint4 wpA = ((const uint4*)WcatT)[tid];
  uint4 wpB = ((const uint4*)WcatT)[512 + tid];
  uint4 wpC;
  const bool hasC = tid < 128;
  if (hasC) wpC = ((const uint4*)WcatT)[1024 + tid];

  // node encoder -> h32
  for (int idx = tid; idx < 8192; idx += 512) {
    int n = idx >> 6, c = idx & 63;
    const float* xr = x + (size_t)(g * 128 + n) * 16;
    float acc = b_node[c];
#pragma unroll
    for (int d = 0; d < 16; ++d) acc += xr[d] * W_node[d * 64 + c];
    h32[n * 68 + c] = acc;
  }

  // per-dst segments: 8-lane group (sub) handles dsts dD0 and dD0+64
  const int dD0 = tid >> 3, sub = tid & 7;
  const int dD1 = dD0 + 64;
  const int ofs0 = offs[g * 129 + dD0];
  const int cnt0 = offs[g * 129 + dD0 + 1] - ofs0;
  const int ofs1 = offs[g * 129 + dD1];
  const int cnt1 = offs[g * 129 + dD1 + 1] - ofs1;
  const int dsw = (dD0 & 7) << 4;  // same for dD1 ((dD0+64)&7 == dD0&7)
  // sortedSR entries are layer/head-invariant: load ONCE into persistent regs
  int sr0_0, sr0_1, sr0_2, sr0_3, sr0_4, sr1_0, sr1_1, sr1_2, sr1_3, sr1_4;
  {
    int p = sub;
    sr0_0 = (p      < cnt0) ? sortedSR[gE + ofs0 + p]      : -1;
    sr0_1 = (p + 8  < cnt0) ? sortedSR[gE + ofs0 + p + 8]  : -1;
    sr0_2 = (p + 16 < cnt0) ? sortedSR[gE + ofs0 + p + 16] : -1;
    sr0_3 = (p + 24 < cnt0) ? sortedSR[gE + ofs0 + p + 24] : -1;
    sr0_4 = (p + 32 < cnt0) ? sortedSR[gE + ofs0 + p + 32] : -1;
    sr1_0 = (p      < cnt1) ? sortedSR[gE + ofs1 + p]      : -1;
    sr1_1 = (p + 8  < cnt1) ? sortedSR[gE + ofs1 + p + 8]  : -1;
    sr1_2 = (p + 16 < cnt1) ? sortedSR[gE + ofs1 + p + 16] : -1;
    sr1_3 = (p + 24 < cnt1) ? sortedSR[gE + ofs1 + p + 24] : -1;
    sr1_4 = (p + 32 < cnt1) ? sortedSR[gE + ofs1 + p + 32] : -1;
  }
  __syncthreads();

  for (int l = 0; l < 4; ++l) {
    // ---- stage hB = bf16(h32): 2 slices of 64 rows
    {
      int row = tid >> 3, c8 = tid & 7;
#pragma unroll
      for (int s2 = 0; s2 < 2; ++s2) {
        int rr = row + s2 * 64;
        const float* hr = &h32[rr * 68 + c8 * 8];
        float4 a0 = *(const float4*)hr, a1 = *(const float4*)(hr + 4);
        uint4 hp;
        hp.x = f2bf(a0.x) | ((unsigned)f2bf(a0.y) << 16);
        hp.y = f2bf(a0.z) | ((unsigned)f2bf(a0.w) << 16);
        hp.z = f2bf(a1.x) | ((unsigned)f2bf(a1.y) << 16);
        hp.w = f2bf(a1.z) | ((unsigned)f2bf(a1.w) << 16);
        *(uint4*)&hB[rr * HBS + c8 * 8] = hp;
      }
    }
    f32x4 accP5_0 = {0.f, 0.f, 0.f, 0.f};
    f32x4 accP5_1 = {0.f, 0.f, 0.f, 0.f};
    f32x4 accP5_2 = {0.f, 0.f, 0.f, 0.f};
    f32x4 accP5_3 = {0.f, 0.f, 0.f, 0.f};
    float4 wsk0, wsk1;
    __syncthreads();  // hB ready (also orders with prev layer's update)

    for (int h = 0; h < 4; ++h) {
      // ---- stage: WT (from prefetch regs) into SS; GhL
      {
        unsigned short* WT = (unsigned short*)SS;
        ((uint4*)WT)[tid] = wpA;
        ((uint4*)WT)[512 + tid] = wpB;
        if (hasC) ((uint4*)WT)[1024 + tid] = wpC;
      }
      GhL[tid] = Gbuf[l * 2048 + h * 512 + tid];
      __syncthreads();

      // ---- P0: qkv GEMM out[node][col] = hB @ WT^T + bias. Wave wv: m-strip m0, 9 n-tiles.
      const unsigned short* WT = (const unsigned short*)SS;
      const float* bcTl = bcatT + (size_t)(l * 4 + h) * WC2;
      f32x4 vf0, vf1, vf2, vf3;
      {
        const short8 a0 = *(const short8*)&hB[(m0 + m16) * HBS + quad * 8];
        const short8 a1 = *(const short8*)&hB[(m0 + m16) * HBS + 32 + quad * 8];
#pragma unroll
        for (int nt = 0; nt < 9; ++nt) {
          int n0 = nt * 16;
          const short8 b0 = *(const short8*)&WT[(n0 + m16) * 64 + quad * 8];
          const short8 b1 = *(const short8*)&WT[(n0 + m16) * 64 + 32 + quad * 8];
          float bias = bcTl[n0 + m16];
          f32x4 acc = {bias, bias, bias, bias};
          acc = __builtin_amdgcn_mfma_f32_16x16x32_bf16(a0, b0, acc, 0, 0, 0);
          acc = __builtin_amdgcn_mfma_f32_16x16x32_bf16(a1, b1, acc, 0, 0, 0);
          if (nt < 4) {
#pragma unroll
            for (int r = 0; r < 4; ++r)
              AV[(m0 + quad * 4 + r) * HBS + n0 + m16] = f2bf(acc[r]);
          } else if (nt == 4) {
            vf0 = acc;
          } else if (nt == 5) {
            vf1 = acc;
          } else if (nt == 6) {
            vf2 = acc;
          } else if (nt == 7) {
            vf3 = acc;
          } else {  // nt == 8: r8 | cD | cS
            if (m16 < 8) {
#pragma unroll
              for (int r = 0; r < 4; ++r) r8L[(m0 + quad * 4 + r) * 8 + m16] = acc[r];
            } else if (m16 == 8) {
#pragma unroll
              for (int r = 0; r < 4; ++r) cDL[m0 + quad * 4 + r] = acc[r];
            } else if (m16 == 9) {
#pragma unroll
              for (int r = 0; r < 4; ++r) cSL[m0 + quad * 4 + r] = acc[r];
            }
          }
        }
      }
      __syncthreads();

      // ---- P1: scores = A @ hB^T -> SS fp32 (col XOR-swizzled)  ||  dense dot(ea,r8)->dotL
      {
        // dense per-edge dot, coalesced (overlaps with MFMAs below)
        {
          int sq = sortedSR[gE + tid];
          int d0 = (sq >> 16) & 127;
          float4 a0 = *(const float4*)(sortedEA + (size_t)(gE + tid) * 8);
          float4 a1 = *(const float4*)(sortedEA + (size_t)(gE + tid) * 8 + 4);
          float4 r80 = *(const float4*)&r8L[d0 * 8];
          float4 r81 = *(const float4*)&r8L[d0 * 8 + 4];
          dotL[tid] = a0.x * r80.x + a0.y * r80.y + a0.z * r80.z + a0.w * r80.w
                    + a1.x * r81.x + a1.y * r81.y + a1.z * r81.z + a1.w * r81.w;
          int e1i = 512 + tid;
          int sq1 = sortedSR[gE + e1i];
          int d1 = (sq1 >> 16) & 127;
          float4 b0 = *(const float4*)(sortedEA + (size_t)(gE + e1i) * 8);
          float4 b1 = *(const float4*)(sortedEA + (size_t)(gE + e1i) * 8 + 4);
          float4 s80 = *(const float4*)&r8L[d1 * 8];
          float4 s81 = *(const float4*)&r8L[d1 * 8 + 4];
          dotL[e1i] = b0.x * s80.x + b0.y * s80.y + b0.z * s80.z + b0.w * s80.w
                    + b1.x * s81.x + b1.y * s81.y + b1.z * s81.z + b1.w * s81.w;
          if (hasC) {
            int e2i = 1024 + tid;
            int sq2 = sortedSR[gE + e2i];
            int d2 = (sq2 >> 16) & 127;
            float4 c0 = *(const float4*)(sortedEA + (size_t)(gE + e2i) * 8);
            float4 c1 = *(const float4*)(sortedEA + (size_t)(gE + e2i) * 8 + 4);
            float4 t80 = *(const float4*)&r8L[d2 * 8];
            float4 t81 = *(const float4*)&r8L[d2 * 8 + 4];
            dotL[e2i] = c0.x * t80.x + c0.y * t80.y + c0.z * t80.z + c0.w * t80.w
                      + c1.x * t81.x + c1.y * t81.y + c1.z * t81.z + c1.w * t81.w;
          }
        }
        const short8 a0 = *(const short8*)&AV[(m0 + m16) * HBS + quad * 8];
        const short8 a1 = *(const short8*)&AV[(m0 + m16) * HBS + 32 + quad * 8];
#pragma unroll
        for (int t = 0; t < 8; ++t) {
          int src0 = t * 16;
          const short8 b0 = *(const short8*)&hB[(src0 + m16) * HBS + quad * 8];
          const short8 b1 = *(const short8*)&hB[(src0 + m16) * HBS + 32 + quad * 8];
          f32x4 acc = {0.f, 0.f, 0.f, 0.f};
          acc = __builtin_amdgcn_mfma_f32_16x16x32_bf16(a0, b0, acc, 0, 0, 0);
          acc = __builtin_amdgcn_mfma_f32_16x16x32_bf16(a1, b1, acc, 0, 0, 0);
#pragma unroll
          for (int r = 0; r < 4; ++r) {
            int row = m0 + quad * 4 + r;
            SS[row * SPF + ((src0 + m16) ^ ((row & 7) << 4))] = acc[r];
          }
        }
      }
      __syncthreads();

      // ---- PD: V-deposit; two per-dst softmaxes (DPP, no atomics); zero+scatter Wmat bf16
      {
        // deposit V frags -> Vt (transposed bf16)
#pragma unroll
        for (int r = 0; r < 4; ++r) AV[(m16) * VTS + m0 + quad * 4 + r] = f2bf(vf0[r]);
#pragma unroll
        for (int r = 0; r < 4; ++r) AV[(16 + m16) * VTS + m0 + quad * 4 + r] = f2bf(vf1[r]);
#pragma unroll
        for (int r = 0; r < 4; ++r) AV[(32 + m16) * VTS + m0 + quad * 4 + r] = f2bf(vf2[r]);
#pragma unroll
        for (int r = 0; r < 4; ++r) AV[(48 + m16) * VTS + m0 + quad * 4 + r] = f2bf(vf3[r]);
        unsigned short* Wu = (unsigned short*)SS;

#define PD_HALF(SRA, SRB, SRC_, SRD_, SRE, OFS, DD)                                        \
        {                                                                                  \
          const int srq[5] = {SRA, SRB, SRC_, SRD_, SRE};                                  \
          float al[5];                                                                     \
          float cD = cDL[DD];                                                              \
          _Pragma("unroll")                                                                \
          for (int it = 0; it < 5; ++it) {                                                 \
            float a = -3.4e38f;                                                            \
            if (srq[it] >= 0) {                                                            \
              int src = srq[it] & 127;                                                     \
              a = SS[(DD) * SPF + (src ^ dsw)] + cD + cSL[src] + dotL[(OFS) + sub + it * 8]; \
            }                                                                              \
            al[it] = a;                                                                    \
          }                                                                                \
          float mx = fmaxf(fmaxf(fmaxf(al[0], al[1]), fmaxf(al[2], al[3])), al[4]);        \
          mx = grp8_max(mx);                                                               \
          float s = 0.f;                                                                   \
          float t8p[8] = {0.f, 0.f, 0.f, 0.f, 0.f, 0.f, 0.f, 0.f};                         \
          _Pragma("unroll")                                                                \
          for (int it = 0; it < 5; ++it) {                                                 \
            float e = 0.f;                                                                 \
            if (srq[it] >= 0) {                                                            \
              e = expf(al[it] - mx);                                                       \
              int eidx = gE + (OFS) + sub + it * 8;                                        \
              float4 e0 = *(const float4*)(sortedEA + (size_t)eidx * 8);                   \
              float4 e1 = *(const float4*)(sortedEA + (size_t)eidx * 8 + 4);               \
              t8p[0] += e * e0.x; t8p[1] += e * e0.y;                                      \
              t8p[2] += e * e0.z; t8p[3] += e * e0.w;                                      \
              t8p[4] += e * e1.x; t8p[5] += e * e1.y;                                      \
              t8p[6] += e * e1.z; t8p[7] += e * e1.w;                                      \
            }                                                                              \
            al[it] = e;                                                                    \
            s += e;                                                                        \
          }                                                                                \
          s = grp8_sum(s);                                                                 \
          _Pragma("unroll")                                                                \
          for (int k = 0; k < 8; ++k) t8p[k] = grp8_sum(t8p[k]);                           \
          float inv = 1.f / fmaxf(s, 1e-16f);                                              \
          if (sub == 0) {                                                                  \
            _Pragma("unroll")                                                              \
            for (int k = 0; k < 8; ++k) t8L[(DD) * 9 + k] = t8p[k] * inv;                  \
            sL[DD] = s;                                                                    \
          }                                                                                \
          __builtin_amdgcn_sched_barrier(0);                                               \
          int rowb = (DD) * 264;                                                           \
          int z0 = (sub * 16) ^ dsw;                                                       \
          uint4 zz = make_uint4(0u, 0u, 0u, 0u);                                           \
          *(uint4*)&Wu[rowb + z0] = zz;                                                    \
          *(uint4*)&Wu[rowb + z0 + 8] = zz;                                                \
          __builtin_amdgcn_sched_barrier(0);                                               \
          bool anyDup = false;                                                             \
          _Pragma("unroll")                                                                \
          for (int it = 0; it < 5; ++it) {                                                 \
            if (srq[it] >= 0) {                                                            \
              int rk = (srq[it] >> 8) & 3;                                                 \
              anyDup |= (rk != 0);                                                         \
              if (rk == 0) Wu[rowb + ((srq[it] & 127) ^ dsw)] = f2bf(al[it] * inv);        \
            }                                                                              \
          }                                                                                \
          if (__any(anyDup)) {                                                             \
            _Pragma("unroll")                                                              \
            for (int rk = 1; rk < 4; ++rk) {                                               \
              __builtin_amdgcn_sched_barrier(0);                                           \
              _Pragma("unroll")                                                            \
              for (int it = 0; it < 5; ++it) {                                             \
                if (srq[it] >= 0 && (((srq[it] >> 8) & 3) == rk)) {                        \
                  int slot = rowb + ((srq[it] & 127) ^ dsw);                               \
                  Wu[slot] = f2bf(bf2f(Wu[slot]) + al[it] * inv);                          \
                }                                                                          \
              }                                                                            \
            }                                                                              \
          }                                                                                \
        }

        PD_HALF(sr0_0, sr0_1, sr0_2, sr0_3, sr0_4, ofs0, dD0)
        PD_HALF(sr1_0, sr1_1, sr1_2, sr1_3, sr1_4, ofs1, dD1)
#undef PD_HALF
      }
      __syncthreads();

      // ---- P5: accP5 += Wmat@Vt (MFMA, 4 col-tiles) + t8@G + (s>0)*bb; prefetch next WT/Wskip
      {
        int nlh = l * 4 + h + 1;
        if (nlh < 16) {
          const uint4* wsrc = (const uint4*)(WcatT + (size_t)nlh * (WC2 * 64));
          wpA = wsrc[tid];
          wpB = wsrc[512 + tid];
          if (hasC) wpC = wsrc[1024 + tid];
        }
        if (h == 3) {
          wsk0 = ((const float4*)(Wskip + (size_t)l * 4096))[tid];
          wsk1 = ((const float4*)(Wskip + (size_t)l * 4096))[512 + tid];
        }
        const unsigned short* Wu = (const unsigned short*)SS;
        int row0 = m0 + m16;
        short8 a_[4];
#pragma unroll
        for (int ks = 0; ks < 4; ++ks)
          a_[ks] = *(const short8*)&Wu[row0 * 264 + (((ks * 32) + quad * 8) ^ ((row0 & 7) << 4))];
#pragma unroll
        for (int t2 = 0; t2 < 4; ++t2) {
          int c0 = t2 * 16;
          f32x4 acc = (t2 == 0) ? accP5_0 : (t2 == 1) ? accP5_1 : (t2 == 2) ? accP5_2 : accP5_3;
#pragma unroll
          for (int ks = 0; ks < 4; ++ks) {
            const short8 b = *(const short8*)&AV[(c0 + m16) * VTS + ks * 32 + quad * 8];
            acc = __builtin_amdgcn_mfma_f32_16x16x32_bf16(a_[ks], b, acc, 0, 0, 0);
          }
          int col = c0 + m16;
          float bbv = bbuf[l * 256 + h * 64 + col];
          float gcol[8];
#pragma unroll
          for (int a8 = 0; a8 < 8; ++a8) gcol[a8] = GhL[a8 * 64 + col];
#pragma unroll
          for (int r = 0; r < 4; ++r) {
            int row = m0 + quad * 4 + r;
            float add = (sL[row] > 0.f) ? bbv : 0.f;
#pragma unroll
            for (int a8 = 0; a8 < 8; ++a8) add += t8L[row * 9 + a8] * gcol[a8];
            acc[r] += add;
          }
          if (t2 == 0) accP5_0 = acc;
          else if (t2 == 1) accP5_1 = acc;
          else if (t2 == 2) accP5_2 = acc;
          else accP5_3 = acc;
        }
      }
      __syncthreads();
    }  // heads

    // ---- update: out = 0.25*acc + h@Wskip+bskip ; vemb ; h += out (all in LDS)
    *(float4*)&SS[tid * 4] = wsk0;         // Wskip_l -> SS[0..2048)
    *(float4*)&SS[2048 + tid * 4] = wsk1;  // Wskip_l -> SS[2048..4096)
    __syncthreads();
    {
      float sk[4][4];
#pragma unroll
      for (int t2 = 0; t2 < 4; ++t2) {
        int col = t2 * 16 + m16;
        float bsv = bskip[l * 64 + col];
#pragma unroll
        for (int r = 0; r < 4; ++r) {
          int row = m0 + quad * 4 + r;
          float s = bsv;
#pragma unroll 8
          for (int d = 0; d < 64; ++d) s += h32[row * 68 + d] * SS[d * 64 + col];
          sk[t2][r] = s;
        }
      }
      __syncthreads();  // all h32 reads done before in-place writes
#pragma unroll
      for (int t2 = 0; t2 < 4; ++t2) {
        int col = t2 * 16 + m16;
#pragma unroll
        for (int r = 0; r < 4; ++r) {
          int row = m0 + quad * 4 + r;
          float av = (t2 == 0) ? accP5_0[r] : (t2 == 1) ? accP5_1[r]
                   : (t2 == 2) ? accP5_2[r] : accP5_3[r];
          float outv = av * 0.25f + sk[t2][r];
          float hnew = outv + h32[row * 68 + col];
          h32[row * 68 + col] = hnew;
          if (row == 127) vembL[l * 64 + col] = outv;
        }
      }
    }
    __syncthreads();
  }  // layers

  // ---- head: pool = vemb @ W_down + b_down; out = sigmoid(pool @ W_out + b_out)
  {
    float part = 0.f;
#pragma unroll
    for (int j2 = 0; j2 < 32; ++j2) {
      int j = wv * 32 + j2;
      part += vembL[j] * Wd[j * 64 + lane];
    }
    SS[wv * 64 + lane] = part;
    __syncthreads();
    if (wv == 0) {
      float acc = bd[lane];
#pragma unroll
      for (int w2 = 0; w2 < 8; ++w2) acc += SS[w2 * 64 + lane];
      float p = acc * Wo[lane];
      p = wave_red_sum(p);
      if (lane == 63) out[g] = 1.f / (1.f + expf(-(p + bo[0])));
    }
  }
}

extern "C" void kernel_launch(void* const* d_in, const int* in_sizes, int n_in,
                              void* d_out, int out_size, void* d_ws, size_t ws_size,
                              hipStream_t stream) {
  const float* x         = (const float*)d_in[0];
  const float* edge_attr = (const float*)d_in[1];
  const int*   ei        = (const int*)d_in[2];
  const float* W_node = (const float*)d_in[4];
  const float* b_node = (const float*)d_in[5];
  const float* W_edge = (const float*)d_in[6];
  const float* b_edge = (const float*)d_in[7];
  const float* Wq = (const float*)d_in[8];
  const float* bq = (const float*)d_in[9];
  const float* Wk = (const float*)d_in[10];
  const float* bk = (const float*)d_in[11];
  const float* Wv = (const float*)d_in[12];
  const float* bv = (const float*)d_in[13];
  const float* We = (const float*)d_in[14];
  const float* be = (const float*)d_in[15];
  const float* Wskip = (const float*)d_in[16];
  const float* bskip = (const float*)d_in[17];
  const float* W_down = (const float*)d_in[18];
  const float* b_down = (const float*)d_in[19];
  const float* W_out  = (const float*)d_in[20];
  const float* b_out  = (const float*)d_in[21];
  float* out = (float*)d_out;

  // workspace carve (~11.2 MB)
  float* p = (float*)d_ws;
  float* Gbuf  = p; p += 8192;
  float* bbuf  = p; p += 1024;
  float* bcatT = p; p += 16 * WC2;                  // 2304 floats
  unsigned short* WcatT = (unsigned short*)p; p += 16 * WC2 * 64 / 2;  // bf16, 294912 B
  int* offsB   = (int*)p; p += 256 * 129;           // 132 KB
  int* sortedSR = (int*)p; p += Ej;                 // 1.18 MB
  float* sortedEA = p; p += (size_t)Ej * 8;         // 9.44 MB

  k_prep2<<<36, 256, 0, stream>>>(We, be, W_edge, b_edge, Gbuf, bbuf);
  k_prepW<<<(16 * WC2 * 64) / 256, 256, 0, stream>>>(Wq, bq, Wk, bk, Wv, bv, Gbuf, bbuf,
                                                     WcatT, bcatT);
  k_sort<<<256, 256, 0, stream>>>(ei, edge_attr, sortedSR, sortedEA, offsB);
  k_fused<<<256, 512, 0, stream>>>(x, W_node, b_node, WcatT, bcatT,
                                   sortedSR, sortedEA, offsB,
                                   Gbuf, bbuf, Wskip, bskip, W_down, b_down, W_out, b_out,
                                   out);
}

// Round 7
// 377.544 us; speedup vs baseline: 1.6201x; 1.0472x over previous
//
#include <hip/hip_runtime.h>
#include <hip/hip_bf16.h>

constexpr int Ej  = 294912;  // total edges
constexpr int EPG = 1152;    // edges per graph
constexpr int WC2 = 144;     // fused-GEMM cols per head: A64 | V64 | r8:8 | cD | cS | pad6
constexpr int SPF = 132;     // scores fp32 row stride (floats); bf16 Wmat row lives at hw d*264
constexpr int HBS = 72;      // hB / A-matrix bf16 row stride (halfwords)
constexpr int VTS = 136;     // Vt bf16 row stride (halfwords)

typedef __attribute__((ext_vector_type(8))) short short8;   // 8 bf16 (MFMA A/B frag)
typedef __attribute__((ext_vector_type(4))) float f32x4;    // MFMA C/D frag

// fp32 -> bf16 bits, round-to-nearest-even
__device__ __forceinline__ unsigned short f2bf(float f) {
  unsigned u = __float_as_uint(f);
  u += 0x7FFFu + ((u >> 16) & 1u);
  return (unsigned short)(u >> 16);
}
__device__ __forceinline__ float bf2f(unsigned short b) {
  return __uint_as_float(((unsigned)b) << 16);
}
// DPP helpers: reductions within aligned 8-lane groups, pure VALU (no LDS pipe).
template <int CTRL>
__device__ __forceinline__ float dppf(float x) {
  return __int_as_float(__builtin_amdgcn_update_dpp(0, __float_as_int(x), CTRL, 0xf, 0xf, true));
}
// 0xB1 = quad_perm xor1, 0x4E = quad_perm xor2, 0x141 = row_half_mirror (i<->7-i in 8)
__device__ __forceinline__ float grp8_sum(float x) {
  x += dppf<0xB1>(x); x += dppf<0x4E>(x); x += dppf<0x141>(x); return x;
}
__device__ __forceinline__ float grp8_max(float x) {
  x = fmaxf(x, dppf<0xB1>(x)); x = fmaxf(x, dppf<0x4E>(x)); x = fmaxf(x, dppf<0x141>(x));
  return x;
}
// 64-lane sum via DPP. Result valid in lane 63.
__device__ __forceinline__ float wave_red_sum(float x) {
  x += __int_as_float(__builtin_amdgcn_update_dpp(0, __float_as_int(x), 0x111, 0xf, 0xf, true));
  x += __int_as_float(__builtin_amdgcn_update_dpp(0, __float_as_int(x), 0x112, 0xf, 0xf, true));
  x += __int_as_float(__builtin_amdgcn_update_dpp(0, __float_as_int(x), 0x114, 0xf, 0xf, true));
  x += __int_as_float(__builtin_amdgcn_update_dpp(0, __float_as_int(x), 0x118, 0xf, 0xf, true));
  x += __int_as_float(__builtin_amdgcn_update_dpp(0, __float_as_int(x), 0x142, 0xf, 0xf, true));
  x += __int_as_float(__builtin_amdgcn_update_dpp(0, __float_as_int(x), 0x143, 0xf, 0xf, true));
  return x;
}

// G[l][h][a][c] = sum_d W_edge[a,d]*We_l[d][h64+c];  bb[l][h][c] = be + b_edge@We
__global__ void k_prep2(const float* __restrict__ We, const float* __restrict__ be,
                        const float* __restrict__ W_edge, const float* __restrict__ b_edge,
                        float* __restrict__ G, float* __restrict__ bb) {
  int tid = blockIdx.x * 256 + threadIdx.x;  // 8192 + 1024
  if (tid < 8192) {
    int l = tid >> 11, rem = tid & 2047;
    int hh = rem >> 9, a = (rem >> 6) & 7, c = rem & 63;
    float acc = 0.f;
#pragma unroll 8
    for (int d = 0; d < 64; ++d)
      acc += W_edge[a * 64 + d] * We[l * 16384 + d * 256 + hh * 64 + c];
    G[tid] = acc;
  } else if (tid < 9216) {
    int t = tid - 8192;
    int l = t >> 8, rem = t & 255;
    int hh = rem >> 6, c = rem & 63;
    float acc = be[l * 256 + hh * 64 + c];
#pragma unroll 8
    for (int d = 0; d < 64; ++d)
      acc += b_edge[d] * We[l * 16384 + d * 256 + hh * 64 + c];
    bb[t] = acc;
  }
}

// WcatT [lh][col][kk] bf16 + bcatT fp32.  (see earlier rounds for column semantics)
__global__ void __launch_bounds__(256) k_prepW(
    const float* __restrict__ Wq, const float* __restrict__ bq,
    const float* __restrict__ Wk, const float* __restrict__ bk,
    const float* __restrict__ Wv, const float* __restrict__ bv,
    const float* __restrict__ Gbuf, const float* __restrict__ bbuf,
    unsigned short* __restrict__ WcatT, float* __restrict__ bcatT) {
  int t = blockIdx.x * 256 + threadIdx.x;  // 16*144*64
  if (t >= 16 * WC2 * 64) return;
  int kk = t & 63;
  int col = (t >> 6) % WC2;
  int lh = t / (WC2 * 64);
  int h = lh & 3, l = lh >> 2;
  const float* Wq_l = Wq + l * 16384;
  const float* Wk_l = Wk + l * 16384;
  const float* bq_l = bq + l * 256;
  const float* bk_l = bk + l * 256;
  float w = 0.f, bias = 0.f;
  if (col < 64) {
    float s = 0.f;
#pragma unroll 8
    for (int i = 0; i < 64; ++i)
      s += Wq_l[kk * 256 + h * 64 + i] * Wk_l[col * 256 + h * 64 + i];
    w = 0.125f * s;
  } else if (col < 128) {
    int j = col - 64;
    w = Wv[l * 16384 + kk * 256 + h * 64 + j];
    bias = bv[l * 256 + h * 64 + j];
  } else if (col < 136) {
    int a = col - 128;
    const float* Grow = Gbuf + l * 2048 + h * 512 + a * 64;
    float s = 0.f, sb = 0.f;
#pragma unroll 8
    for (int i = 0; i < 64; ++i) {
      s  += Wq_l[kk * 256 + h * 64 + i] * Grow[i];
      sb += bq_l[h * 64 + i] * Grow[i];
    }
    w = 0.125f * s; bias = 0.125f * sb;
  } else if (col == 136) {
    float s = 0.f, sb = 0.f;
#pragma unroll 8
    for (int i = 0; i < 64; ++i) {
      float bkb = bk_l[h * 64 + i] + bbuf[l * 256 + h * 64 + i];
      s  += Wq_l[kk * 256 + h * 64 + i] * bkb;
      sb += bq_l[h * 64 + i] * bkb;
    }
    w = 0.125f * s; bias = 0.125f * sb;
  } else if (col == 137) {
    float s = 0.f;
#pragma unroll 8
    for (int i = 0; i < 64; ++i)
      s += Wk_l[kk * 256 + h * 64 + i] * bq_l[h * 64 + i];
    w = 0.125f * s;
  }
  WcatT[(size_t)(lh * WC2 + col) * 64 + kk] = f2bf(w);
  if (kk == 0) bcatT[lh * WC2 + col] = bias;
}

// Sort each graph's edges by dst (dup-rank per (dst,src) via 16K cursor). Emits
// sortedSR (src | duprank<<8 | dst<<16), sortedEA, offs[g][129]. LDS 66 KB.
__global__ void __launch_bounds__(256) k_sort(const int* __restrict__ ei,
                                              const float* __restrict__ edge_attr,
                                              int* __restrict__ sortedSR,
                                              float* __restrict__ sortedEA,
                                              int* __restrict__ offs) {
  __shared__ unsigned cursor[16384];  // (dst,src) dup-rank, 64 KB
  __shared__ unsigned cnt[128];       // per-dst count -> scatter cursor
  __shared__ unsigned base[129];
  int g = blockIdx.x, tid = threadIdx.x;
  for (int i = tid; i < 16384; i += 256) cursor[i] = 0u;
  if (tid < 128) cnt[tid] = 0u;
  __syncthreads();
  for (int e = tid; e < EPG; e += 256) {
    int d = ei[Ej + g * EPG + e] - g * 128;
    atomicAdd(&cnt[d], 1u);
  }
  __syncthreads();
  if (tid == 0) {
    unsigned run = 0;
    for (int j = 0; j < 128; ++j) { base[j] = run; run += cnt[j]; }
    base[128] = run;
  }
  __syncthreads();
  if (tid < 128) { offs[g * 129 + tid] = (int)base[tid]; cnt[tid] = base[tid]; }
  if (tid == 0) offs[g * 129 + 128] = EPG;
  __syncthreads();
  for (int e = tid; e < EPG; e += 256) {
    int s = ei[g * EPG + e] - g * 128;
    int d = ei[Ej + g * EPG + e] - g * 128;
    unsigned pos = atomicAdd(&cnt[d], 1u);
    unsigned r = atomicAdd(&cursor[d * 128 + s], 1u);
    sortedSR[g * EPG + pos] = s | ((int)min(r, 3u) << 8) | (d << 16);
    const float4* ep = (const float4*)(edge_attr + ((size_t)g * EPG + e) * 8);
    float4* op = (float4*)(sortedEA + ((size_t)g * EPG + pos) * 8);
    op[0] = ep[0]; op[1] = ep[1];
  }
}

// One block per graph, 512 threads (8 waves, 2/SIMD, 256-reg budget). 4 barriers/head:
// P0 qkv GEMM (WT direct from global) | P1 scores MFMA + dense dot(ea,r8) + GhL stage |
// PD per-dst softmax (fully scalarized, batched loads, DPP reductions, no atomics) |
// P5 Wmat@Vt MFMA + epilogue. LDS 157184 B -> 1 block/CU.
__global__ void __launch_bounds__(512, 2) k_fused(
    const float* __restrict__ x, const float* __restrict__ W_node, const float* __restrict__ b_node,
    const unsigned short* __restrict__ WcatT, const float* __restrict__ bcatT,
    const int* __restrict__ sortedSR, const float* __restrict__ sortedEA,
    const int* __restrict__ offs,
    const float* __restrict__ Gbuf, const float* __restrict__ bbuf,
    const float* __restrict__ Wskip, const float* __restrict__ bskip,
    const float* __restrict__ Wd, const float* __restrict__ bd,
    const float* __restrict__ Wo, const float* __restrict__ bo,
    float* __restrict__ out) {
  __shared__ float SS[128 * SPF];           // 67584 B: scores fp32 / Wmat bf16 (in-row) / Wskip
  __shared__ float h32[128 * 68];           // 34816 B: resident fp32 h
  __shared__ unsigned short hB[128 * HBS];  // 18432 B: bf16 h
  __shared__ unsigned short AV[128 * HBS];  // 18432 B: A-matrix (P0-P1) then Vt 64xVTS (PD-P5)
  __shared__ float r8L[128 * 8];            // 4096
  __shared__ float t8L[128 * 9];            // 4608
  __shared__ float dotL[EPG];               // 4608: dot(ea, r8[dst]) per sorted edge
  __shared__ float sL[128];                 // 512
  __shared__ float cDL[128];                // 512
  __shared__ float cSL[128];                // 512
  __shared__ float GhL[512];                // 2048
  __shared__ float vembL[256];              // 1024

  int g = blockIdx.x, tid = threadIdx.x;
  int lane = tid & 63, m16 = lane & 15, quad = lane >> 4, wv = tid >> 6;  // wv 0..7
  const int m0 = wv * 16;  // this wave's m-strip / dst-strip everywhere
  const int gE = g * EPG;

  // node encoder -> h32
  for (int idx = tid; idx < 8192; idx += 512) {
    int n = idx >> 6, c = idx & 63;
    const float* xr = x + (size_t)(g * 128 + n) * 16;
    float acc = b_node[c];
#pragma unroll
    for (int d = 0; d < 16; ++d) acc += xr[d] * W_node[d * 64 + c];
    h32[n * 68 + c] = acc;
  }

  // per-dst segments: 8-lane group handles dsts dD0 and dD0+64
  const int dD0 = tid >> 3, sub = tid & 7;
  const int dD1 = dD0 + 64;
  const int ofs0 = offs[g * 129 + dD0];
  const int ofs1 = offs[g * 129 + dD1];
  const int dsw = (dD0 & 7) << 4;  // XOR swizzle; same for dD1
  // sortedSR entries are layer/head-invariant: load ONCE into persistent named regs
  int sr0_0, sr0_1, sr0_2, sr0_3, sr0_4, sr1_0, sr1_1, sr1_2, sr1_3, sr1_4;
  {
    int cnt0 = offs[g * 129 + dD0 + 1] - ofs0;
    int cnt1 = offs[g * 129 + dD1 + 1] - ofs1;
    int p = sub;
    sr0_0 = (p      < cnt0) ? sortedSR[gE + ofs0 + p]      : -1;
    sr0_1 = (p + 8  < cnt0) ? sortedSR[gE + ofs0 + p + 8]  : -1;
    sr0_2 = (p + 16 < cnt0) ? sortedSR[gE + ofs0 + p + 16] : -1;
    sr0_3 = (p + 24 < cnt0) ? sortedSR[gE + ofs0 + p + 24] : -1;
    sr0_4 = (p + 32 < cnt0) ? sortedSR[gE + ofs0 + p + 32] : -1;
    sr1_0 = (p      < cnt1) ? sortedSR[gE + ofs1 + p]      : -1;
    sr1_1 = (p + 8  < cnt1) ? sortedSR[gE + ofs1 + p + 8]  : -1;
    sr1_2 = (p + 16 < cnt1) ? sortedSR[gE + ofs1 + p + 16] : -1;
    sr1_3 = (p + 24 < cnt1) ? sortedSR[gE + ofs1 + p + 24] : -1;
    sr1_4 = (p + 32 < cnt1) ? sortedSR[gE + ofs1 + p + 32] : -1;
  }
  // dense-dot pass dst bytes (layer/head-invariant)
  const int ddA = (sortedSR[gE + tid] >> 16) & 127;
  const int ddB = (sortedSR[gE + 512 + tid] >> 16) & 127;
  const bool hasC = tid < 128;
  const int ddC = hasC ? ((sortedSR[gE + 1024 + tid] >> 16) & 127) : 0;
  __syncthreads();

  for (int l = 0; l < 4; ++l) {
    // ---- stage hB = bf16(h32): 2 slices of 64 rows
    {
      int row = tid >> 3, c8 = tid & 7;
#pragma unroll
      for (int s2 = 0; s2 < 2; ++s2) {
        int rr = row + s2 * 64;
        const float* hr = &h32[rr * 68 + c8 * 8];
        float4 a0 = *(const float4*)hr, a1 = *(const float4*)(hr + 4);
        uint4 hp;
        hp.x = f2bf(a0.x) | ((unsigned)f2bf(a0.y) << 16);
        hp.y = f2bf(a0.z) | ((unsigned)f2bf(a0.w) << 16);
        hp.z = f2bf(a1.x) | ((unsigned)f2bf(a1.y) << 16);
        hp.w = f2bf(a1.z) | ((unsigned)f2bf(a1.w) << 16);
        *(uint4*)&hB[rr * HBS + c8 * 8] = hp;
      }
    }
    f32x4 accP5_0 = {0.f, 0.f, 0.f, 0.f};
    f32x4 accP5_1 = {0.f, 0.f, 0.f, 0.f};
    f32x4 accP5_2 = {0.f, 0.f, 0.f, 0.f};
    f32x4 accP5_3 = {0.f, 0.f, 0.f, 0.f};
    float4 wsk0, wsk1;
    __syncthreads();  // hB ready

    for (int h = 0; h < 4; ++h) {
      const int lh = l * 4 + h;
      // ---- P0: qkv GEMM; WT/bias direct from global (L2-hot). 9 n-tiles per wave.
      const unsigned short* WTg = WcatT + (size_t)lh * (WC2 * 64);
      const float* bcTl = bcatT + (size_t)lh * WC2;
      f32x4 vf0, vf1, vf2, vf3;
      {
        const short8 ha0 = *(const short8*)&hB[(m0 + m16) * HBS + quad * 8];
        const short8 ha1 = *(const short8*)&hB[(m0 + m16) * HBS + 32 + quad * 8];
#pragma unroll
        for (int nt = 0; nt < 9; ++nt) {
          int n0 = nt * 16;
          const unsigned short* wb = WTg + (size_t)(n0 + m16) * 64 + quad * 8;
          const short8 b0 = *(const short8*)wb;
          const short8 b1 = *(const short8*)(wb + 32);
          float bias = bcTl[n0 + m16];
          f32x4 acc = {bias, bias, bias, bias};
          acc = __builtin_amdgcn_mfma_f32_16x16x32_bf16(ha0, b0, acc, 0, 0, 0);
          acc = __builtin_amdgcn_mfma_f32_16x16x32_bf16(ha1, b1, acc, 0, 0, 0);
          if (nt < 4) {
#pragma unroll
            for (int r = 0; r < 4; ++r)
              AV[(m0 + quad * 4 + r) * HBS + n0 + m16] = f2bf(acc[r]);
          } else if (nt == 4) {
            vf0 = acc;
          } else if (nt == 5) {
            vf1 = acc;
          } else if (nt == 6) {
            vf2 = acc;
          } else if (nt == 7) {
            vf3 = acc;
          } else {  // nt == 8: r8 | cD | cS
            if (m16 < 8) {
#pragma unroll
              for (int r = 0; r < 4; ++r) r8L[(m0 + quad * 4 + r) * 8 + m16] = acc[r];
            } else if (m16 == 8) {
#pragma unroll
              for (int r = 0; r < 4; ++r) cDL[m0 + quad * 4 + r] = acc[r];
            } else if (m16 == 9) {
#pragma unroll
              for (int r = 0; r < 4; ++r) cSL[m0 + quad * 4 + r] = acc[r];
            }
          }
        }
      }
      __syncthreads();  // r8L/cDL/cSL complete (cross-wave for dotL/PD)

      // ---- P1: scores MFMA -> SS (col XOR-swizzled) || dense dot(ea,r8)->dotL || GhL stage
      {
        {
          float4 a0 = *(const float4*)(sortedEA + (size_t)(gE + tid) * 8);
          float4 a1 = *(const float4*)(sortedEA + (size_t)(gE + tid) * 8 + 4);
          float4 r80 = *(const float4*)&r8L[ddA * 8];
          float4 r81 = *(const float4*)&r8L[ddA * 8 + 4];
          dotL[tid] = a0.x * r80.x + a0.y * r80.y + a0.z * r80.z + a0.w * r80.w
                    + a1.x * r81.x + a1.y * r81.y + a1.z * r81.z + a1.w * r81.w;
          float4 b0 = *(const float4*)(sortedEA + (size_t)(gE + 512 + tid) * 8);
          float4 b1 = *(const float4*)(sortedEA + (size_t)(gE + 512 + tid) * 8 + 4);
          float4 s80 = *(const float4*)&r8L[ddB * 8];
          float4 s81 = *(const float4*)&r8L[ddB * 8 + 4];
          dotL[512 + tid] = b0.x * s80.x + b0.y * s80.y + b0.z * s80.z + b0.w * s80.w
                          + b1.x * s81.x + b1.y * s81.y + b1.z * s81.z + b1.w * s81.w;
          if (hasC) {
            float4 c0 = *(const float4*)(sortedEA + (size_t)(gE + 1024 + tid) * 8);
            float4 c1 = *(const float4*)(sortedEA + (size_t)(gE + 1024 + tid) * 8 + 4);
            float4 t80 = *(const float4*)&r8L[ddC * 8];
            float4 t81 = *(const float4*)&r8L[ddC * 8 + 4];
            dotL[1024 + tid] = c0.x * t80.x + c0.y * t80.y + c0.z * t80.z + c0.w * t80.w
                             + c1.x * t81.x + c1.y * t81.y + c1.z * t81.z + c1.w * t81.w;
          }
        }
        GhL[tid] = Gbuf[l * 2048 + h * 512 + tid];
        const short8 sa0 = *(const short8*)&AV[(m0 + m16) * HBS + quad * 8];
        const short8 sa1 = *(const short8*)&AV[(m0 + m16) * HBS + 32 + quad * 8];
#pragma unroll
        for (int t = 0; t < 8; ++t) {
          int src0 = t * 16;
          const short8 b0 = *(const short8*)&hB[(src0 + m16) * HBS + quad * 8];
          const short8 b1 = *(const short8*)&hB[(src0 + m16) * HBS + 32 + quad * 8];
          f32x4 acc = {0.f, 0.f, 0.f, 0.f};
          acc = __builtin_amdgcn_mfma_f32_16x16x32_bf16(sa0, b0, acc, 0, 0, 0);
          acc = __builtin_amdgcn_mfma_f32_16x16x32_bf16(sa1, b1, acc, 0, 0, 0);
#pragma unroll
          for (int r = 0; r < 4; ++r) {
            int row = m0 + quad * 4 + r;
            SS[row * SPF + ((src0 + m16) ^ ((row & 7) << 4))] = acc[r];
          }
        }
      }
      __syncthreads();

      // ---- PD: V-deposit; two per-dst softmaxes, fully scalarized, batched loads
      {
#pragma unroll
        for (int r = 0; r < 4; ++r) AV[(m16) * VTS + m0 + quad * 4 + r] = f2bf(vf0[r]);
#pragma unroll
        for (int r = 0; r < 4; ++r) AV[(16 + m16) * VTS + m0 + quad * 4 + r] = f2bf(vf1[r]);
#pragma unroll
        for (int r = 0; r < 4; ++r) AV[(32 + m16) * VTS + m0 + quad * 4 + r] = f2bf(vf2[r]);
#pragma unroll
        for (int r = 0; r < 4; ++r) AV[(48 + m16) * VTS + m0 + quad * 4 + r] = f2bf(vf3[r]);
        unsigned short* Wu = (unsigned short*)SS;

        // subphase A: all LDS loads for both halves (unpredicated, in-bounds by construction)
        int s00 = sr0_0 & 127, s01 = sr0_1 & 127, s02 = sr0_2 & 127, s03 = sr0_3 & 127,
            s04 = sr0_4 & 127;
        int s10 = sr1_0 & 127, s11 = sr1_1 & 127, s12 = sr1_2 & 127, s13 = sr1_3 & 127,
            s14 = sr1_4 & 127;
        float sc00 = SS[dD0 * SPF + (s00 ^ dsw)], sc01 = SS[dD0 * SPF + (s01 ^ dsw)],
              sc02 = SS[dD0 * SPF + (s02 ^ dsw)], sc03 = SS[dD0 * SPF + (s03 ^ dsw)],
              sc04 = SS[dD0 * SPF + (s04 ^ dsw)];
        float sc10 = SS[dD1 * SPF + (s10 ^ dsw)], sc11 = SS[dD1 * SPF + (s11 ^ dsw)],
              sc12 = SS[dD1 * SPF + (s12 ^ dsw)], sc13 = SS[dD1 * SPF + (s13 ^ dsw)],
              sc14 = SS[dD1 * SPF + (s14 ^ dsw)];
        float dt00 = dotL[ofs0 + sub],      dt01 = dotL[ofs0 + sub + 8],
              dt02 = dotL[ofs0 + sub + 16], dt03 = dotL[ofs0 + sub + 24],
              dt04 = dotL[ofs0 + sub + 32];
        float dt10 = dotL[ofs1 + sub],      dt11 = dotL[ofs1 + sub + 8],
              dt12 = dotL[ofs1 + sub + 16], dt13 = dotL[ofs1 + sub + 24],
              dt14 = dotL[ofs1 + sub + 32];
        float cs00 = cSL[s00], cs01 = cSL[s01], cs02 = cSL[s02], cs03 = cSL[s03],
              cs04 = cSL[s04];
        float cs10 = cSL[s10], cs11 = cSL[s11], cs12 = cSL[s12], cs13 = cSL[s13],
              cs14 = cSL[s14];
        float cD0 = cDL[dD0], cD1 = cDL[dD1];

        // alphas
        float al00 = (sr0_0 >= 0) ? sc00 + cD0 + cs00 + dt00 : -3.4e38f;
        float al01 = (sr0_1 >= 0) ? sc01 + cD0 + cs01 + dt01 : -3.4e38f;
        float al02 = (sr0_2 >= 0) ? sc02 + cD0 + cs02 + dt02 : -3.4e38f;
        float al03 = (sr0_3 >= 0) ? sc03 + cD0 + cs03 + dt03 : -3.4e38f;
        float al04 = (sr0_4 >= 0) ? sc04 + cD0 + cs04 + dt04 : -3.4e38f;
        float al10 = (sr1_0 >= 0) ? sc10 + cD1 + cs10 + dt10 : -3.4e38f;
        float al11 = (sr1_1 >= 0) ? sc11 + cD1 + cs11 + dt11 : -3.4e38f;
        float al12 = (sr1_2 >= 0) ? sc12 + cD1 + cs12 + dt12 : -3.4e38f;
        float al13 = (sr1_3 >= 0) ? sc13 + cD1 + cs13 + dt13 : -3.4e38f;
        float al14 = (sr1_4 >= 0) ? sc14 + cD1 + cs14 + dt14 : -3.4e38f;
        float mx0 = grp8_max(fmaxf(fmaxf(fmaxf(al00, al01), fmaxf(al02, al03)), al04));
        float mx1 = grp8_max(fmaxf(fmaxf(fmaxf(al10, al11), fmaxf(al12, al13)), al14));

        // exp + transient ea reload + unnormalized t8 accum (no LDS stores yet)
        float t8a0 = 0.f, t8a1 = 0.f, t8a2 = 0.f, t8a3 = 0.f, t8a4 = 0.f, t8a5 = 0.f,
              t8a6 = 0.f, t8a7 = 0.f;
        float t8b0 = 0.f, t8b1 = 0.f, t8b2 = 0.f, t8b3 = 0.f, t8b4 = 0.f, t8b5 = 0.f,
              t8b6 = 0.f, t8b7 = 0.f;
        float e00 = 0.f, e01 = 0.f, e02 = 0.f, e03 = 0.f, e04 = 0.f;
        float e10 = 0.f, e11 = 0.f, e12 = 0.f, e13 = 0.f, e14 = 0.f;
#define EXPT8(E, SR, OFS, IT, AL, MX, T0, T1, T2, T3, T4, T5, T6, T7)                  \
        if (SR >= 0) {                                                                 \
          E = __expf(AL - MX);                                                         \
          const float* ep = sortedEA + (size_t)(gE + (OFS) + sub + (IT)*8) * 8;        \
          float4 p0 = *(const float4*)ep;                                              \
          float4 p1 = *(const float4*)(ep + 4);                                        \
          T0 += E * p0.x; T1 += E * p0.y; T2 += E * p0.z; T3 += E * p0.w;              \
          T4 += E * p1.x; T5 += E * p1.y; T6 += E * p1.z; T7 += E * p1.w;              \
        }
        EXPT8(e00, sr0_0, ofs0, 0, al00, mx0, t8a0, t8a1, t8a2, t8a3, t8a4, t8a5, t8a6, t8a7)
        EXPT8(e01, sr0_1, ofs0, 1, al01, mx0, t8a0, t8a1, t8a2, t8a3, t8a4, t8a5, t8a6, t8a7)
        EXPT8(e02, sr0_2, ofs0, 2, al02, mx0, t8a0, t8a1, t8a2, t8a3, t8a4, t8a5, t8a6, t8a7)
        EXPT8(e03, sr0_3, ofs0, 3, al03, mx0, t8a0, t8a1, t8a2, t8a3, t8a4, t8a5, t8a6, t8a7)
        EXPT8(e04, sr0_4, ofs0, 4, al04, mx0, t8a0, t8a1, t8a2, t8a3, t8a4, t8a5, t8a6, t8a7)
        EXPT8(e10, sr1_0, ofs1, 0, al10, mx1, t8b0, t8b1, t8b2, t8b3, t8b4, t8b5, t8b6, t8b7)
        EXPT8(e11, sr1_1, ofs1, 1, al11, mx1, t8b0, t8b1, t8b2, t8b3, t8b4, t8b5, t8b6, t8b7)
        EXPT8(e12, sr1_2, ofs1, 2, al12, mx1, t8b0, t8b1, t8b2, t8b3, t8b4, t8b5, t8b6, t8b7)
        EXPT8(e13, sr1_3, ofs1, 3, al13, mx1, t8b0, t8b1, t8b2, t8b3, t8b4, t8b5, t8b6, t8b7)
        EXPT8(e14, sr1_4, ofs1, 4, al14, mx1, t8b0, t8b1, t8b2, t8b3, t8b4, t8b5, t8b6, t8b7)
#undef EXPT8
        float s0 = grp8_sum(e00 + e01 + e02 + e03 + e04);
        float s1 = grp8_sum(e10 + e11 + e12 + e13 + e14);
        t8a0 = grp8_sum(t8a0); t8a1 = grp8_sum(t8a1); t8a2 = grp8_sum(t8a2);
        t8a3 = grp8_sum(t8a3); t8a4 = grp8_sum(t8a4); t8a5 = grp8_sum(t8a5);
        t8a6 = grp8_sum(t8a6); t8a7 = grp8_sum(t8a7);
        t8b0 = grp8_sum(t8b0); t8b1 = grp8_sum(t8b1); t8b2 = grp8_sum(t8b2);
        t8b3 = grp8_sum(t8b3); t8b4 = grp8_sum(t8b4); t8b5 = grp8_sum(t8b5);
        t8b6 = grp8_sum(t8b6); t8b7 = grp8_sum(t8b7);
        float inv0 = 1.f / fmaxf(s0, 1e-16f);
        float inv1 = 1.f / fmaxf(s1, 1e-16f);

        // stores: t8L/sL, then zero rows, then scatter (DS in-order per wave; stores
        // to may-aliasing addresses keep program order -> no fences needed)
        if (sub == 0) {
          t8L[dD0 * 9 + 0] = t8a0 * inv0; t8L[dD0 * 9 + 1] = t8a1 * inv0;
          t8L[dD0 * 9 + 2] = t8a2 * inv0; t8L[dD0 * 9 + 3] = t8a3 * inv0;
          t8L[dD0 * 9 + 4] = t8a4 * inv0; t8L[dD0 * 9 + 5] = t8a5 * inv0;
          t8L[dD0 * 9 + 6] = t8a6 * inv0; t8L[dD0 * 9 + 7] = t8a7 * inv0;
          sL[dD0] = s0;
          t8L[dD1 * 9 + 0] = t8b0 * inv1; t8L[dD1 * 9 + 1] = t8b1 * inv1;
          t8L[dD1 * 9 + 2] = t8b2 * inv1; t8L[dD1 * 9 + 3] = t8b3 * inv1;
          t8L[dD1 * 9 + 4] = t8b4 * inv1; t8L[dD1 * 9 + 5] = t8b5 * inv1;
          t8L[dD1 * 9 + 6] = t8b6 * inv1; t8L[dD1 * 9 + 7] = t8b7 * inv1;
          sL[dD1] = s1;
        }
        int rowb0 = dD0 * 264, rowb1 = dD1 * 264;
        int z0 = (sub * 16) ^ dsw;
        uint4 zz = make_uint4(0u, 0u, 0u, 0u);
        *(uint4*)&Wu[rowb0 + z0] = zz;
        *(uint4*)&Wu[rowb0 + z0 + 8] = zz;
        *(uint4*)&Wu[rowb1 + z0] = zz;
        *(uint4*)&Wu[rowb1 + z0 + 8] = zz;
        bool dup = false;
#define SCAT(SR, E, INV, ROWB)                                                         \
        if (SR >= 0) {                                                                 \
          int rk = (SR >> 8) & 3;                                                      \
          dup |= (rk != 0);                                                            \
          if (rk == 0) Wu[(ROWB) + (((SR) & 127) ^ dsw)] = f2bf((E) * (INV));          \
        }
        SCAT(sr0_0, e00, inv0, rowb0) SCAT(sr0_1, e01, inv0, rowb0)
        SCAT(sr0_2, e02, inv0, rowb0) SCAT(sr0_3, e03, inv0, rowb0)
        SCAT(sr0_4, e04, inv0, rowb0)
        SCAT(sr1_0, e10, inv1, rowb1) SCAT(sr1_1, e11, inv1, rowb1)
        SCAT(sr1_2, e12, inv1, rowb1) SCAT(sr1_3, e13, inv1, rowb1)
        SCAT(sr1_4, e14, inv1, rowb1)
#undef SCAT
        if (__any(dup)) {  // rare duplicate (dst,src): rank-ordered accumulate
#pragma unroll
          for (int rk = 1; rk < 4; ++rk) {
#define DUPA(SR, E, INV, ROWB)                                                         \
            if (SR >= 0 && (((SR >> 8) & 3) == rk)) {                                  \
              int sl = (ROWB) + (((SR) & 127) ^ dsw);                                  \
              Wu[sl] = f2bf(bf2f(Wu[sl]) + (E) * (INV));                               \
            }
            DUPA(sr0_0, e00, inv0, rowb0) DUPA(sr0_1, e01, inv0, rowb0)
            DUPA(sr0_2, e02, inv0, rowb0) DUPA(sr0_3, e03, inv0, rowb0)
            DUPA(sr0_4, e04, inv0, rowb0)
            DUPA(sr1_0, e10, inv1, rowb1) DUPA(sr1_1, e11, inv1, rowb1)
            DUPA(sr1_2, e12, inv1, rowb1) DUPA(sr1_3, e13, inv1, rowb1)
            DUPA(sr1_4, e14, inv1, rowb1)
#undef DUPA
          }
        }
      }
      __syncthreads();

      // ---- P5: accP5 += Wmat@Vt (MFMA, 4 col-tiles) + t8@G + (s>0)*bb
      {
        if (h == 3) {
          wsk0 = ((const float4*)(Wskip + (size_t)l * 4096))[tid];
          wsk1 = ((const float4*)(Wskip + (size_t)l * 4096))[512 + tid];
        }
        const unsigned short* Wu = (const unsigned short*)SS;
        int row0 = m0 + m16;
        short8 a_[4];
#pragma unroll
        for (int ks = 0; ks < 4; ++ks)
          a_[ks] = *(const short8*)&Wu[row0 * 264 + (((ks * 32) + quad * 8) ^ ((row0 & 7) << 4))];
#pragma unroll
        for (int t2 = 0; t2 < 4; ++t2) {
          int c0 = t2 * 16;
          f32x4 acc = (t2 == 0) ? accP5_0 : (t2 == 1) ? accP5_1 : (t2 == 2) ? accP5_2 : accP5_3;
#pragma unroll
          for (int ks = 0; ks < 4; ++ks) {
            const short8 b = *(const short8*)&AV[(c0 + m16) * VTS + ks * 32 + quad * 8];
            acc = __builtin_amdgcn_mfma_f32_16x16x32_bf16(a_[ks], b, acc, 0, 0, 0);
          }
          int col = c0 + m16;
          float bbv = bbuf[l * 256 + h * 64 + col];
          float gcol[8];
#pragma unroll
          for (int a8 = 0; a8 < 8; ++a8) gcol[a8] = GhL[a8 * 64 + col];
#pragma unroll
          for (int r = 0; r < 4; ++r) {
            int row = m0 + quad * 4 + r;
            float add = (sL[row] > 0.f) ? bbv : 0.f;
#pragma unroll
            for (int a8 = 0; a8 < 8; ++a8) add += t8L[row * 9 + a8] * gcol[a8];
            acc[r] += add;
          }
          if (t2 == 0) accP5_0 = acc;
          else if (t2 == 1) accP5_1 = acc;
          else if (t2 == 2) accP5_2 = acc;
          else accP5_3 = acc;
        }
      }
      __syncthreads();
    }  // heads

    // ---- update: out = 0.25*acc + h@Wskip+bskip ; vemb ; h += out (all in LDS)
    *(float4*)&SS[tid * 4] = wsk0;         // Wskip_l -> SS[0..2048)
    *(float4*)&SS[2048 + tid * 4] = wsk1;  // Wskip_l -> SS[2048..4096)
    __syncthreads();
    {
      float sk[4][4];
#pragma unroll
      for (int t2 = 0; t2 < 4; ++t2) {
        int col = t2 * 16 + m16;
        float bsv = bskip[l * 64 + col];
#pragma unroll
        for (int r = 0; r < 4; ++r) {
          int row = m0 + quad * 4 + r;
          float s = bsv;
#pragma unroll 8
          for (int d = 0; d < 64; ++d) s += h32[row * 68 + d] * SS[d * 64 + col];
          sk[t2][r] = s;
        }
      }
      __syncthreads();  // all h32 reads done before in-place writes
#pragma unroll
      for (int t2 = 0; t2 < 4; ++t2) {
        int col = t2 * 16 + m16;
#pragma unroll
        for (int r = 0; r < 4; ++r) {
          int row = m0 + quad * 4 + r;
          float av = (t2 == 0) ? accP5_0[r] : (t2 == 1) ? accP5_1[r]
                   : (t2 == 2) ? accP5_2[r] : accP5_3[r];
          float outv = av * 0.25f + sk[t2][r];
          float hnew = outv + h32[row * 68 + col];
          h32[row * 68 + col] = hnew;
          if (row == 127) vembL[l * 64 + col] = outv;
        }
      }
    }
    __syncthreads();
  }  // layers

  // ---- head: pool = vemb @ W_down + b_down; out = sigmoid(pool @ W_out + b_out)
  {
    float part = 0.f;
#pragma unroll
    for (int j2 = 0; j2 < 32; ++j2) {
      int j = wv * 32 + j2;
      part += vembL[j] * Wd[j * 64 + lane];
    }
    SS[wv * 64 + lane] = part;
    __syncthreads();
    if (wv == 0) {
      float acc = bd[lane];
#pragma unroll
      for (int w2 = 0; w2 < 8; ++w2) acc += SS[w2 * 64 + lane];
      float p = acc * Wo[lane];
      p = wave_red_sum(p);
      if (lane == 63) out[g] = 1.f / (1.f + expf(-(p + bo[0])));
    }
  }
}

extern "C" void kernel_launch(void* const* d_in, const int* in_sizes, int n_in,
                              void* d_out, int out_size, void* d_ws, size_t ws_size,
                              hipStream_t stream) {
  const float* x         = (const float*)d_in[0];
  const float* edge_attr = (const float*)d_in[1];
  const int*   ei        = (const int*)d_in[2];
  const float* W_node = (const float*)d_in[4];
  const float* b_node = (const float*)d_in[5];
  const float* W_edge = (const float*)d_in[6];
  const float* b_edge = (const float*)d_in[7];
  const float* Wq = (const float*)d_in[8];
  const float* bq = (const float*)d_in[9];
  const float* Wk = (const float*)d_in[10];
  const float* bk = (const float*)d_in[11];
  const float* Wv = (const float*)d_in[12];
  const float* bv = (const float*)d_in[13];
  const float* We = (const float*)d_in[14];
  const float* be = (const float*)d_in[15];
  const float* Wskip = (const float*)d_in[16];
  const float* bskip = (const float*)d_in[17];
  const float* W_down = (const float*)d_in[18];
  const float* b_down = (const float*)d_in[19];
  const float* W_out  = (const float*)d_in[20];
  const float* b_out  = (const float*)d_in[21];
  float* out = (float*)d_out;

  // workspace carve (~11.2 MB)
  float* p = (float*)d_ws;
  float* Gbuf  = p; p += 8192;
  float* bbuf  = p; p += 1024;
  float* bcatT = p; p += 16 * WC2;                  // 2304 floats
  unsigned short* WcatT = (unsigned short*)p; p += 16 * WC2 * 64 / 2;  // bf16, 294912 B
  int* offsB   = (int*)p; p += 256 * 129;           // 132 KB
  int* sortedSR = (int*)p; p += Ej;                 // 1.18 MB
  float* sortedEA = p; p += (size_t)Ej * 8;         // 9.44 MB

  k_prep2<<<36, 256, 0, stream>>>(We, be, W_edge, b_edge, Gbuf, bbuf);
  k_prepW<<<(16 * WC2 * 64) / 256, 256, 0, stream>>>(Wq, bq, Wk, bk, Wv, bv, Gbuf, bbuf,
                                                     WcatT, bcatT);
  k_sort<<<256, 256, 0, stream>>>(ei, edge_attr, sortedSR, sortedEA, offsB);
  k_fused<<<256, 512, 0, stream>>>(x, W_node, b_node, WcatT, bcatT,
                                   sortedSR, sortedEA, offsB,
                                   Gbuf, bbuf, Wskip, bskip, W_down, b_down, W_out, b_out,
                                   out);
}